// Round 17
// baseline (128.157 us; speedup 1.0000x reference)
//
#include <hip/hip_runtime.h>

#define B_ 16
#define C_ 512
#define N_ 1024

typedef __attribute__((ext_vector_type(8))) short bf16x8_t;
typedef __attribute__((ext_vector_type(4))) float f32x4_t;

__device__ __forceinline__ unsigned short f2bf(float f) {
  unsigned int u = __float_as_uint(f);
  u += 0x7fffu + ((u >> 16) & 1u);
  return (unsigned short)(u >> 16);
}

__device__ __forceinline__ f32x4_t mfma16(bf16x8_t a, bf16x8_t b, f32x4_t c) {
  return __builtin_amdgcn_mfma_f32_16x16x32_bf16(a, b, c, 0, 0, 0);
}

// async global->LDS, 16B per lane; dest is wave-uniform base (lane*16 added by HW)
__device__ __forceinline__ void gload_lds16(const void* g, void* l) {
  __builtin_amdgcn_global_load_lds(
      (const __attribute__((address_space(1))) unsigned int*)g,
      (__attribute__((address_space(3))) unsigned int*)l, 16, 0, 0);
}

// ---------------------------------------------------------------- weights cast
// Wq|Wk|Wv -> FRAG-BLOCKED stacked buffer (12 tiles of 128 rows):
//   elem(m_stacked, k) at tile = m_stacked>>7, off = tile*65536 +
//   ((m&127)>>4)<<13 | (k>>3)<<7 | (m&15)<<3 | (k&7)
// so the qkv GEMM can load A fragments directly from L2 (1KB/wave, no LDS).
// Wp stays linear for gemm_proj. Thread: one row, 8 consecutive k.
__global__ __launch_bounds__(256) void castw_k(
    const float* __restrict__ qw, const float* __restrict__ kw,
    const float* __restrict__ vw, const float* __restrict__ pw,
    unsigned short* __restrict__ Wf, unsigned short* __restrict__ Wp) {
  int idx = blockIdx.x * 256 + threadIdx.x;  // grid 128 -> 32768 threads
  int m = idx >> 6;          // row 0..511
  int k0 = (idx & 63) * 8;   // k octet base
  long lin = (long)m * 512 + k0;
  long foff = ((long)((m & 127) >> 4) << 13) + ((k0 >> 3) << 7) + ((m & 15) << 3);
  int mt = m >> 7;  // 0..3 : which 128-row tile within a weight
#pragma unroll
  for (int s = 0; s < 3; ++s) {
    const float* src = s == 0 ? qw : (s == 1 ? kw : vw);
    float4 a = *(const float4*)(src + lin);
    float4 b2 = *(const float4*)(src + lin + 4);
    unsigned short us[8] = {f2bf(a.x),  f2bf(a.y),  f2bf(a.z),  f2bf(a.w),
                            f2bf(b2.x), f2bf(b2.y), f2bf(b2.z), f2bf(b2.w)};
    *(uint4*)(Wf + (long)(s * 4 + mt) * 65536 + foff) = *(uint4*)us;
  }
  float4 d = *(const float4*)(pw + lin);
  float4 d2 = *(const float4*)(pw + lin + 4);
  unsigned short up[8] = {f2bf(d.x),  f2bf(d.y),  f2bf(d.z),  f2bf(d.w),
                          f2bf(d2.x), f2bf(d2.y), f2bf(d2.z), f2bf(d2.w)};
  *(uint4*)(Wp + lin) = *(uint4*)up;
}

// ---------------------------------------------------------------- fused GN
__global__ __launch_bounds__(512, 1) void gn_fused_k(
    const float* __restrict__ x, const float* __restrict__ gw,
    const float* __restrict__ gb, unsigned short* __restrict__ hn) {
  int blk = blockIdx.x;
  int b = blk >> 4, gp = blk & 15;
  int t = threadIdx.x, lane = t & 63, wave = t >> 6;
  __shared__ float xs[32768];      // [c][n ^ (((c>>3)&3)<<4)] = 128KB
  __shared__ float red[2][2][8];   // [sum/sq][group][wave]
  const float* xg = x + ((long)b * C_ + gp * 32) * N_;  // 128KB contiguous
  float s0 = 0.f, s20 = 0.f, s1 = 0.f, s21 = 0.f;
#pragma unroll
  for (int i = 0; i < 16; ++i) {
    int f4 = t + 512 * i;
    float4 v = ((const float4*)xg)[f4];
    float sum = v.x + v.y + v.z + v.w;
    float sq = v.x * v.x + v.y * v.y + v.z * v.z + v.w * v.w;
    if (i < 8) { s0 += sum; s20 += sq; } else { s1 += sum; s21 += sq; }
    int fi = f4 << 2;
    int c = fi >> 10, n = fi & 1023;
    int nx = n ^ (((c >> 3) & 3) << 4);
    *(float4*)&xs[(c << 10) + nx] = v;
  }
#pragma unroll
  for (int m = 1; m < 64; m <<= 1) {
    s0 += __shfl_xor(s0, m); s20 += __shfl_xor(s20, m);
    s1 += __shfl_xor(s1, m); s21 += __shfl_xor(s21, m);
  }
  if (lane == 0) {
    red[0][0][wave] = s0; red[1][0][wave] = s20;
    red[0][1][wave] = s1; red[1][1][wave] = s21;
  }
  __syncthreads();
  float m0 = 0.f, v0 = 0.f, m1 = 0.f, v1 = 0.f;
#pragma unroll
  for (int w = 0; w < 8; ++w) {
    m0 += red[0][0][w]; v0 += red[1][0][w];
    m1 += red[0][1][w]; v1 += red[1][1][w];
  }
  m0 *= (1.f / 16384.f); m1 *= (1.f / 16384.f);
  float rv0 = rsqrtf(v0 * (1.f / 16384.f) - m0 * m0 + 1e-5f);
  float rv1 = rsqrtf(v1 * (1.f / 16384.f) - m1 * m1 + 1e-5f);
  int q = t & 3;
  float mean = (q >> 1) ? m1 : m0, rv = (q >> 1) ? rv1 : rv0;
  float ga[8], be[8];
#pragma unroll
  for (int jj = 0; jj < 8; ++jj) {
    int gc = gp * 32 + q * 8 + jj;
    ga[jj] = gw[gc] * rv;
    be[jj] = gb[gc] - mean * ga[jj];
  }
  unsigned short* ob = hn + (long)b * N_ * C_ + gp * 32 + q * 8;
  int n0 = t >> 2;  // 0..127
  for (int it = 0; it < 8; ++it) {
    int n = n0 + (it << 7);
    int nsw = n ^ (q << 4);
    unsigned short us[8];
#pragma unroll
    for (int jj = 0; jj < 8; ++jj) {
      int c = q * 8 + jj;
      us[jj] = f2bf(xs[(c << 10) + nsw] * ga[jj] + be[jj]);
    }
    *(uint4*)(ob + (long)n * C_) = *(uint4*)us;
  }
}

// ---------------------------------------------------------------- QKV GEMM
// A fragments DIRECT from L2 (frag-blocked Wf, 1KB wave loads, no A-LDS);
// B (HN) double-buffered in LDS (2x16KB): per kt, issue ks0 A-loads, then
// stage B(kt+1) into the other buffer, compute (A-waits leave the stage in
// flight; vmcnt retires in issue order), ONE barrier per kt. Slabs 0/1 (Q,K)
// normal MFMA; slab 2 (V) transposed MFMA -> all epilogue stores ushort4.
__global__ __launch_bounds__(256) void gemm_qkv(
    const unsigned short* __restrict__ Wf, const unsigned short* __restrict__ HN,
    const float* __restrict__ qb, const float* __restrict__ kb,
    const float* __restrict__ vb, unsigned short* __restrict__ Q2,
    unsigned short* __restrict__ K2, unsigned short* __restrict__ V2,
    float scale) {
  int flat = blockIdx.x + 12 * (blockIdx.y + 8 * blockIdx.z);  // 1536 = 8*192
  int nf = (flat & 7) * 192 + (flat >> 3);
  int bxi = nf % 12, rem = nf / 12;
  int byi = rem & 7, bz = rem >> 3;
  const unsigned short* Bb = HN + (long)bz * N_ * C_ + (long)byi * 128 * 512;
  __shared__ char lds[32768];  // two 16KB B buffers
  int tid = threadIdx.x;
  int lane = tid & 63, wave = tid >> 6;
  int wr = wave >> 1, wc = wave & 1;
  int lrow = lane & 15, kgrp = lane >> 4;
  int slab = bxi >> 2;
  f32x4_t acc[4][4];
#pragma unroll
  for (int i = 0; i < 4; ++i)
#pragma unroll
    for (int j = 0; j < 4; ++j) acc[i][j] = (f32x4_t){0.f, 0.f, 0.f, 0.f};

  // A fragment base: wave's 64 rows start at wr*64 within the 128-row tile
  const unsigned short* Af =
      Wf + (long)bxi * 65536 + (long)(wr * 4) * 8192 + lane * 8;

  int perm = (((lane & 7) ^ (lane >> 3)) << 3);
  const unsigned short* Bsrc = Bb + (long)(wave * 32 + (lane >> 3)) * 512 + perm;
  char* Bdst0 = lds + wave * 4096;
  char* Bdst1 = lds + 16384 + wave * 4096;

  // prologue: stage B tile 0
#pragma unroll
  for (int i = 0; i < 4; ++i)
    gload_lds16(Bsrc + (long)i * 8 * 512, Bdst0 + i * 1024);
  __syncthreads();

  for (int kt = 0; kt < 8; ++kt) {
    char* cur = lds + ((kt & 1) ? 16384 : 0);
    char* nxtd = ((kt & 1) ? Bdst0 : Bdst1);
    // ---- issue ks=0 A loads first (retire before the stage drains) ----
    bf16x8_t af0[4];
#pragma unroll
    for (int mi = 0; mi < 4; ++mi)
      af0[mi] = *(const bf16x8_t*)(Af + mi * 8192 + (kt * 2) * 512);
    // ---- stage next B tile into the other buffer ----
    if (kt < 7) {
#pragma unroll
      for (int i = 0; i < 4; ++i)
        gload_lds16(Bsrc + (long)i * 8 * 512 + (kt + 1) * 64, nxtd + i * 1024);
    }
    // ---- compute ks = 0 ----
    bf16x8_t bfv[4];
#pragma unroll
    for (int ni = 0; ni < 4; ++ni) {
      int r = wc * 64 + ni * 16 + lrow;
      int o = r * 128 + kgrp * 16;
      o ^= (r & 7) << 4;
      bfv[ni] = *(bf16x8_t*)(cur + o);
    }
    if (slab < 2) {
#pragma unroll
      for (int mi = 0; mi < 4; ++mi)
#pragma unroll
        for (int ni = 0; ni < 4; ++ni)
          acc[mi][ni] = mfma16(af0[mi], bfv[ni], acc[mi][ni]);
    } else {
#pragma unroll
      for (int ni = 0; ni < 4; ++ni)
#pragma unroll
        for (int mi = 0; mi < 4; ++mi)
          acc[ni][mi] = mfma16(bfv[ni], af0[mi], acc[ni][mi]);
    }
    // ---- compute ks = 1 ----
    bf16x8_t af1[4];
#pragma unroll
    for (int mi = 0; mi < 4; ++mi)
      af1[mi] = *(const bf16x8_t*)(Af + mi * 8192 + (kt * 2 + 1) * 512);
#pragma unroll
    for (int ni = 0; ni < 4; ++ni) {
      int r = wc * 64 + ni * 16 + lrow;
      int o = r * 128 + 64 + kgrp * 16;
      o ^= (r & 7) << 4;
      bfv[ni] = *(bf16x8_t*)(cur + o);
    }
    if (slab < 2) {
#pragma unroll
      for (int mi = 0; mi < 4; ++mi)
#pragma unroll
        for (int ni = 0; ni < 4; ++ni)
          acc[mi][ni] = mfma16(af1[mi], bfv[ni], acc[mi][ni]);
    } else {
#pragma unroll
      for (int ni = 0; ni < 4; ++ni)
#pragma unroll
        for (int mi = 0; mi < 4; ++mi)
          acc[ni][mi] = mfma16(bfv[ni], af1[mi], acc[ni][mi]);
    }
    __syncthreads();  // next tile staged + all reads of cur done
  }

  if (slab < 2) {
    const float* bias = slab == 0 ? qb : kb;
    float scl = slab == 0 ? scale : 1.f;
    int rowloc = (bxi & 3) * 128 + wr * 64;  // c within slab
    int colbase = byi * 128 + wc * 64;       // n
    unsigned short* ob = (slab == 0 ? Q2 : K2) + ((long)bz << 19);
#pragma unroll
    for (int mi = 0; mi < 4; ++mi) {
#pragma unroll
      for (int ni = 0; ni < 4; ++ni) {
        int row0 = rowloc + mi * 16 + kgrp * 4;
        int col = colbase + ni * 16 + lrow;
        unsigned short us[4];
#pragma unroll
        for (int rg = 0; rg < 4; ++rg)
          us[rg] = f2bf((acc[mi][ni][rg] + bias[row0 + rg]) * scl);
        long off = ((long)(col >> 4) << 13) + ((long)(row0 >> 3) << 7) +
                   ((col & 15) << 3) + (row0 & 7);
        *(ushort4*)(ob + off) = make_ushort4(us[0], us[1], us[2], us[3]);
      }
    }
  } else {
    int cbase = (bxi & 3) * 128 + wr * 64;  // c
    int nbase = byi * 128 + wc * 64;        // n
    unsigned short* ob = V2 + ((long)bz << 19);
#pragma unroll
    for (int ni = 0; ni < 4; ++ni) {
#pragma unroll
      for (int mi = 0; mi < 4; ++mi) {
        int n0 = nbase + ni * 16 + kgrp * 4;
        int c = cbase + mi * 16 + lrow;
        float bv = vb[c];
        unsigned short us[4];
#pragma unroll
        for (int rg = 0; rg < 4; ++rg) us[rg] = f2bf(acc[ni][mi][rg] + bv);
        long off = ((long)(c >> 4) << 14) + ((long)(n0 >> 3) << 7) +
                   ((c & 15) << 3) + (n0 & 7);
        *(ushort4*)(ob + off) = make_ushort4(us[0], us[1], us[2], us[3]);
      }
    }
  }
}

// ---------------------------------------------------------------- fused attn+PV
// 256 blocks x 512 threads (8 waves, 2/SIMD); b = f&15 pins batch to XCD b%8.
// Q LDS-staged into P2 region; K direct frag-blocked 1KB wave loads; P2
// (128KB) overlays Q after a barrier. No softmax max-subtraction (scores
// ~N(0,1.44) in exp2 domain -> huge headroom; p/sum identical). Transposed
// QK^T (mfma(kf,qa)) -> ushort4 P stores + 2-stage sum reduce.
__global__ __launch_bounds__(512, 1) void attn_pv_k(
    const unsigned short* __restrict__ q2, const unsigned short* __restrict__ k2,
    const unsigned short* __restrict__ v2, unsigned short* __restrict__ ao) {
  int f = blockIdx.x;
  int b = f & 15, ib = f >> 4;  // rows ib*64..+64
  int tid = threadIdx.x, lane = tid & 63, wave = tid >> 6;  // 8 waves
  int lrow = lane & 15, kgrp = lane >> 4;
  __shared__ unsigned short P2[65536];  // 128KB; first 64KB doubles as Q stage
  __shared__ float red1[8][64];
  __shared__ float invr[64];
  // ---- stage Q: 64KB contiguous -> P2[0..32768) linear ----
  {
    const unsigned short* qsrc =
        q2 + ((long)b << 19) + ((long)(ib * 4) << 13) + wave * 4096 + lane * 8;
    char* qdst = (char*)P2 + wave * 8192;
#pragma unroll
    for (int i = 0; i < 8; ++i) gload_lds16(qsrc + i * 512, qdst + i * 1024);
  }
  asm volatile("s_waitcnt vmcnt(0)" ::: "memory");
  __syncthreads();
  f32x4_t acc[4][8];
#pragma unroll
  for (int h = 0; h < 4; ++h)
#pragma unroll
    for (int t = 0; t < 8; ++t) acc[h][t] = (f32x4_t){0.f, 0.f, 0.f, 0.f};
  const unsigned short* kb =
      k2 + ((long)b << 19) + ((long)(wave * 8) << 13) + lane * 8;
  for (int ks = 0; ks < 16; ++ks) {  // K = 512
    bf16x8_t kf[8];
#pragma unroll
    for (int t = 0; t < 8; ++t)
      kf[t] = *(const bf16x8_t*)(kb + t * 8192 + ks * 512);
    bf16x8_t qa[4];
#pragma unroll
    for (int h = 0; h < 4; ++h)
      qa[h] = *(const bf16x8_t*)&P2[h * 8192 + ks * 512 + lane * 8];
    __builtin_amdgcn_s_setprio(1);
#pragma unroll
    for (int h = 0; h < 4; ++h)
#pragma unroll
      for (int t = 0; t < 8; ++t) acc[h][t] = mfma16(kf[t], qa[h], acc[h][t]);
    __builtin_amdgcn_s_setprio(0);
  }
  // acc[h][t][rg] = score[j = wave*128 + t*16 + kgrp*4 + rg][i = h*16 + lrow]
  __syncthreads();  // all waves past K-loop: Q dead, P2 region writable
  // ---- exp2 (no max subtraction) + vectorized P stage + row sums ----
  float sm[4] = {0.f, 0.f, 0.f, 0.f};
#pragma unroll
  for (int h = 0; h < 4; ++h) {
#pragma unroll
    for (int t = 0; t < 8; ++t) {
      int jb = wave * 16 + t * 2 + (kgrp >> 1);
      int off = h * 16384 + jb * 128 + (((lrow ^ (jb & 7)) << 3) | ((kgrp & 1) << 2));
      unsigned short us[4];
#pragma unroll
      for (int rg = 0; rg < 4; ++rg) {
        float p = exp2f(acc[h][t][rg]);  // scores already in log2 domain
        sm[h] += p;
        us[rg] = f2bf(p);
      }
      *(ushort4*)&P2[off] = make_ushort4(us[0], us[1], us[2], us[3]);
    }
  }
#pragma unroll
  for (int m = 16; m < 64; m <<= 1)
#pragma unroll
    for (int h = 0; h < 4; ++h) sm[h] += __shfl_xor(sm[h], m);
  if (kgrp == 0) {
#pragma unroll
    for (int h = 0; h < 4; ++h) red1[wave][h * 16 + lrow] = sm[h];
  }
  __syncthreads();  // P2 + red1 complete
  if (tid < 64) {
    float s = red1[0][tid];
#pragma unroll
    for (int w = 1; w < 8; ++w) s += red1[w][tid];
    invr[tid] = 1.f / s;
  }
  __syncthreads();
  // ---- PV: wave owns channels [wave*64, +64), 2-deep V prefetch ----
  f32x4_t o[4][4];
#pragma unroll
  for (int h = 0; h < 4; ++h)
#pragma unroll
    for (int cf = 0; cf < 4; ++cf) o[h][cf] = (f32x4_t){0.f, 0.f, 0.f, 0.f};
  const char* vb2 =
      (const char*)(v2 + ((long)b << 19) + ((long)(wave * 4) << 14)) + lane * 16;
  bf16x8_t vc[4];
#pragma unroll
  for (int cf = 0; cf < 4; ++cf) vc[cf] = *(const bf16x8_t*)(vb2 + cf * 32768);
#pragma unroll
  for (int js = 0; js < 32; ++js) {
    bf16x8_t vn[4];
    if (js < 31) {
#pragma unroll
      for (int cf = 0; cf < 4; ++cf)
        vn[cf] = *(const bf16x8_t*)(vb2 + cf * 32768 + (js + 1) * 1024);
    }
    int jb = js * 4 + kgrp;
    int pox = ((lrow ^ (jb & 7)) << 3) + jb * 128;
    bf16x8_t pa[4];
#pragma unroll
    for (int h = 0; h < 4; ++h)
      pa[h] = *(const bf16x8_t*)&P2[h * 16384 + pox];
    __builtin_amdgcn_s_setprio(1);
#pragma unroll
    for (int h = 0; h < 4; ++h)
#pragma unroll
      for (int cf = 0; cf < 4; ++cf)
        o[h][cf] = mfma16(pa[h], vc[cf], o[h][cf]);
    __builtin_amdgcn_s_setprio(0);
    if (js < 31) {
#pragma unroll
      for (int cf = 0; cf < 4; ++cf) vc[cf] = vn[cf];
    }
  }
  float inv[4][4];
#pragma unroll
  for (int h = 0; h < 4; ++h)
#pragma unroll
    for (int rg = 0; rg < 4; ++rg)
      inv[h][rg] = invr[h * 16 + kgrp * 4 + rg];
  unsigned short* aob = ao + ((long)(b * N_ + ib * 64)) * C_;
#pragma unroll
  for (int h = 0; h < 4; ++h)
#pragma unroll
    for (int cf = 0; cf < 4; ++cf) {
      int c = wave * 64 + cf * 16 + lrow;
#pragma unroll
      for (int rg = 0; rg < 4; ++rg) {
        int i = h * 16 + kgrp * 4 + rg;
        aob[(long)i * C_ + c] = f2bf(o[h][cf][rg] * inv[h][rg]);
      }
    }
}

// ---------------------------------------------------------------- proj GEMM
// out = x + Wp*AO^T + pb (fp32, (b,c,n)); A=Wp (512x512), B=AO (b,n,c).
__global__ __launch_bounds__(256) void gemm_proj(
    const unsigned short* __restrict__ A, const unsigned short* __restrict__ Bm,
    const float* __restrict__ bias, const float* __restrict__ resid,
    float* __restrict__ outp) {
  int flat = blockIdx.x + 4 * (blockIdx.y + 8 * blockIdx.z);  // 512 = 8*64
  int nf = (flat & 7) * 64 + (flat >> 3);
  int bxi = nf & 3, byi = (nf >> 2) & 7, bz = nf >> 5;
  const unsigned short* Ab = A + (long)bxi * 128 * 512;
  const unsigned short* Bb = Bm + (long)bz * N_ * C_ + (long)byi * 128 * 512;
  __shared__ char lds[32768];
  char* As = lds;
  char* Bs = lds + 16384;
  int tid = threadIdx.x;
  int lane = tid & 63, wave = tid >> 6;
  int wr = wave >> 1, wc = wave & 1;
  int lrow = lane & 15, kgrp = lane >> 4;
  f32x4_t acc[4][4];
#pragma unroll
  for (int i = 0; i < 4; ++i)
#pragma unroll
    for (int j = 0; j < 4; ++j) acc[i][j] = (f32x4_t){0.f, 0.f, 0.f, 0.f};

  int perm = (((lane & 7) ^ (lane >> 3)) << 3);
  const unsigned short* Asrc = Ab + (long)(wave * 32 + (lane >> 3)) * 512 + perm;
  const unsigned short* Bsrc = Bb + (long)(wave * 32 + (lane >> 3)) * 512 + perm;
  char* Adst = As + wave * 32 * 128;
  char* Bdst = Bs + wave * 32 * 128;

  for (int kt = 0; kt < 8; ++kt) {
    __syncthreads();
#pragma unroll
    for (int i = 0; i < 4; ++i) {
      gload_lds16(Asrc + (long)i * 8 * 512 + kt * 64, Adst + i * 1024);
      gload_lds16(Bsrc + (long)i * 8 * 512 + kt * 64, Bdst + i * 1024);
    }
    __syncthreads();
#pragma unroll
    for (int ks = 0; ks < 2; ++ks) {
      bf16x8_t af[4], bfv[4];
#pragma unroll
      for (int mi = 0; mi < 4; ++mi) {
        int r = wr * 64 + mi * 16 + lrow;
        int o = r * 128 + ks * 64 + kgrp * 16;
        o ^= (r & 7) << 4;
        af[mi] = *(bf16x8_t*)(As + o);
      }
#pragma unroll
      for (int ni = 0; ni < 4; ++ni) {
        int r = wc * 64 + ni * 16 + lrow;
        int o = r * 128 + ks * 64 + kgrp * 16;
        o ^= (r & 7) << 4;
        bfv[ni] = *(bf16x8_t*)(Bs + o);
      }
#pragma unroll
      for (int mi = 0; mi < 4; ++mi)
#pragma unroll
        for (int ni = 0; ni < 4; ++ni)
          acc[mi][ni] = mfma16(af[mi], bfv[ni], acc[mi][ni]);
    }
  }

  int rowbase = bxi * 128 + wr * 64;
  int colbase = byi * 128 + wc * 64;
  float* ob = outp + (long)bz * C_ * N_;
  const float* rb = resid + (long)bz * C_ * N_;
#pragma unroll
  for (int mi = 0; mi < 4; ++mi) {
#pragma unroll
    for (int ni = 0; ni < 4; ++ni) {
      int row0 = rowbase + mi * 16 + kgrp * 4;
      int col = colbase + ni * 16 + lrow;
#pragma unroll
      for (int rg = 0; rg < 4; ++rg) {
        int r = row0 + rg;
        ob[(long)r * N_ + col] =
            acc[mi][ni][rg] + bias[r] + rb[(long)r * N_ + col];
      }
    }
  }
}

// ---------------------------------------------------------------- launch
extern "C" void kernel_launch(void* const* d_in, const int* in_sizes, int n_in,
                              void* d_out, int out_size, void* d_ws,
                              size_t ws_size, hipStream_t stream) {
  (void)in_sizes; (void)n_in; (void)out_size; (void)ws_size;
  const float* x = (const float*)d_in[0];
  const float* nw = (const float*)d_in[1];
  const float* nb = (const float*)d_in[2];
  const float* qw = (const float*)d_in[3];
  const float* qbias = (const float*)d_in[4];
  const float* kw = (const float*)d_in[5];
  const float* kbias = (const float*)d_in[6];
  const float* vw = (const float*)d_in[7];
  const float* vbias = (const float*)d_in[8];
  const float* pw = (const float*)d_in[9];
  const float* pbias = (const float*)d_in[10];
  float* out = (float*)d_out;

  char* ws = (char*)d_ws;
  unsigned short* WQKVf = (unsigned short*)(ws + 0);       // 1.5MB frag-blocked
  unsigned short* Wp = (unsigned short*)(ws + 1572864);    // 0.5MB linear
  unsigned short* HN = (unsigned short*)(ws + 2097152);    // 16MB (b,n,c)
  unsigned short* Q2 = (unsigned short*)(ws + 18874368);   // 16MB frag [n/16][c/8]
  unsigned short* K2 = (unsigned short*)(ws + 35651584);   // 16MB frag [n/16][c/8]
  unsigned short* V2 = (unsigned short*)(ws + 52428800);   // 16MB frag [c/16][n/8]
  unsigned short* AO = (unsigned short*)(ws + 69206016);   // 16MB (b,n,c)

  castw_k<<<128, 256, 0, stream>>>(qw, kw, vw, pw, WQKVf, Wp);
  gn_fused_k<<<256, 512, 0, stream>>>(x, nw, nb, HN);

  // 512^-0.5 * log2(e): scores land in the exp2 domain for native exp2f
  const float scale = 0.06375871512f;
  // q,k,v in one dispatch (A direct from L2, B double-buffered)
  gemm_qkv<<<dim3(12, 8, B_), 256, 0, stream>>>(WQKVf, HN, qbias, kbias, vbias,
                                                Q2, K2, V2, scale);
  // fused QK^T + softmax + PV -> AO (b,n,c)
  attn_pv_k<<<256, 512, 0, stream>>>(Q2, K2, V2, AO);
  // out = x + Wp*AO^T + pb (fp32, (b,c,n))
  gemm_proj<<<dim3(4, 8, B_), 256, 0, stream>>>(Wp, AO, pbias, x, out);
}

// Round 18
// 110.949 us; speedup vs baseline: 1.1551x; 1.1551x over previous
//
#include <hip/hip_runtime.h>

#define B_ 16
#define C_ 512
#define N_ 1024

typedef __attribute__((ext_vector_type(8))) short bf16x8_t;
typedef __attribute__((ext_vector_type(4))) float f32x4_t;

__device__ __forceinline__ unsigned short f2bf(float f) {
  unsigned int u = __float_as_uint(f);
  u += 0x7fffu + ((u >> 16) & 1u);
  return (unsigned short)(u >> 16);
}

__device__ __forceinline__ f32x4_t mfma16(bf16x8_t a, bf16x8_t b, f32x4_t c) {
  return __builtin_amdgcn_mfma_f32_16x16x32_bf16(a, b, c, 0, 0, 0);
}

// async global->LDS, 16B per lane; dest is wave-uniform base (lane*16 added by HW)
__device__ __forceinline__ void gload_lds16(const void* g, void* l) {
  __builtin_amdgcn_global_load_lds(
      (const __attribute__((address_space(1))) unsigned int*)g,
      (__attribute__((address_space(3))) unsigned int*)l, 16, 0, 0);
}

// ---------------------------------------------------------------- weights cast
// Vectorized (float4 in, ushort4 out). Stacks Wq|Wk|Wv (linear) for qkv GEMM.
__global__ __launch_bounds__(256) void castw_k(
    const float* __restrict__ qw, const float* __restrict__ kw,
    const float* __restrict__ vw, const float* __restrict__ pw,
    unsigned short* __restrict__ Wqkv, unsigned short* __restrict__ Wp) {
  int i = (blockIdx.x * 256 + threadIdx.x) * 4;  // 262144 elements each
  float4 a = *(const float4*)(qw + i);
  float4 b = *(const float4*)(kw + i);
  float4 c = *(const float4*)(vw + i);
  float4 d = *(const float4*)(pw + i);
  *(ushort4*)(Wqkv + i) = make_ushort4(f2bf(a.x), f2bf(a.y), f2bf(a.z), f2bf(a.w));
  *(ushort4*)(Wqkv + 262144 + i) =
      make_ushort4(f2bf(b.x), f2bf(b.y), f2bf(b.z), f2bf(b.w));
  *(ushort4*)(Wqkv + 524288 + i) =
      make_ushort4(f2bf(c.x), f2bf(c.y), f2bf(c.z), f2bf(c.w));
  *(ushort4*)(Wp + i) = make_ushort4(f2bf(d.x), f2bf(d.y), f2bf(d.z), f2bf(d.w));
}

// ---------------------------------------------------------------- fused GN
__global__ __launch_bounds__(512, 1) void gn_fused_k(
    const float* __restrict__ x, const float* __restrict__ gw,
    const float* __restrict__ gb, unsigned short* __restrict__ hn) {
  int blk = blockIdx.x;
  int b = blk >> 4, gp = blk & 15;
  int t = threadIdx.x, lane = t & 63, wave = t >> 6;
  __shared__ float xs[32768];      // [c][n ^ (((c>>3)&3)<<4)] = 128KB
  __shared__ float red[2][2][8];   // [sum/sq][group][wave]
  const float* xg = x + ((long)b * C_ + gp * 32) * N_;  // 128KB contiguous
  float s0 = 0.f, s20 = 0.f, s1 = 0.f, s21 = 0.f;
#pragma unroll
  for (int i = 0; i < 16; ++i) {
    int f4 = t + 512 * i;
    float4 v = ((const float4*)xg)[f4];
    float sum = v.x + v.y + v.z + v.w;
    float sq = v.x * v.x + v.y * v.y + v.z * v.z + v.w * v.w;
    if (i < 8) { s0 += sum; s20 += sq; } else { s1 += sum; s21 += sq; }
    int fi = f4 << 2;
    int c = fi >> 10, n = fi & 1023;
    int nx = n ^ (((c >> 3) & 3) << 4);
    *(float4*)&xs[(c << 10) + nx] = v;
  }
#pragma unroll
  for (int m = 1; m < 64; m <<= 1) {
    s0 += __shfl_xor(s0, m); s20 += __shfl_xor(s20, m);
    s1 += __shfl_xor(s1, m); s21 += __shfl_xor(s21, m);
  }
  if (lane == 0) {
    red[0][0][wave] = s0; red[1][0][wave] = s20;
    red[0][1][wave] = s1; red[1][1][wave] = s21;
  }
  __syncthreads();
  float m0 = 0.f, v0 = 0.f, m1 = 0.f, v1 = 0.f;
#pragma unroll
  for (int w = 0; w < 8; ++w) {
    m0 += red[0][0][w]; v0 += red[1][0][w];
    m1 += red[0][1][w]; v1 += red[1][1][w];
  }
  m0 *= (1.f / 16384.f); m1 *= (1.f / 16384.f);
  float rv0 = rsqrtf(v0 * (1.f / 16384.f) - m0 * m0 + 1e-5f);
  float rv1 = rsqrtf(v1 * (1.f / 16384.f) - m1 * m1 + 1e-5f);
  int q = t & 3;
  float mean = (q >> 1) ? m1 : m0, rv = (q >> 1) ? rv1 : rv0;
  float ga[8], be[8];
#pragma unroll
  for (int jj = 0; jj < 8; ++jj) {
    int gc = gp * 32 + q * 8 + jj;
    ga[jj] = gw[gc] * rv;
    be[jj] = gb[gc] - mean * ga[jj];
  }
  unsigned short* ob = hn + (long)b * N_ * C_ + gp * 32 + q * 8;
  int n0 = t >> 2;  // 0..127
  for (int it = 0; it < 8; ++it) {
    int n = n0 + (it << 7);
    int nsw = n ^ (q << 4);
    unsigned short us[8];
#pragma unroll
    for (int jj = 0; jj < 8; ++jj) {
      int c = q * 8 + jj;
      us[jj] = f2bf(xs[(c << 10) + nsw] * ga[jj] + be[jj]);
    }
    *(uint4*)(ob + (long)n * C_) = *(uint4*)us;
  }
}

// ---------------------------------------------------------------- QKV GEMM
// Merged single dispatch; A+B LDS-staged, DOUBLE-BUFFERED (2x32KB): prologue
// stages tile 0; per kt, stage(kt+1) into the other buffer BEFORE computing
// kt, then ONE __syncthreads (drain overlaps 32 MFMAs across ~8 waves/CU).
// T3-minimum-2-phase pattern (m248v2, +10% refcheck'd). Slabs 0/1 (Q,K)
// normal MFMA; slab 2 (V) transposed MFMA -> all epilogue stores ushort4.
__global__ __launch_bounds__(256) void gemm_qkv(
    const unsigned short* __restrict__ W, const unsigned short* __restrict__ HN,
    const float* __restrict__ qb, const float* __restrict__ kb,
    const float* __restrict__ vb, unsigned short* __restrict__ Q2,
    unsigned short* __restrict__ K2, unsigned short* __restrict__ V2,
    float scale) {
  int flat = blockIdx.x + 12 * (blockIdx.y + 8 * blockIdx.z);  // 1536 = 8*192
  int nf = (flat & 7) * 192 + (flat >> 3);
  int bxi = nf % 12, rem = nf / 12;
  int byi = rem & 7, bz = rem >> 3;
  const unsigned short* Ab = W + (long)bxi * 128 * 512;
  const unsigned short* Bb = HN + (long)bz * N_ * C_ + (long)byi * 128 * 512;
  __shared__ char lds[65536];  // 2 buffers x (16KB A + 16KB B)
  int tid = threadIdx.x;
  int lane = tid & 63, wave = tid >> 6;
  int wr = wave >> 1, wc = wave & 1;
  int lrow = lane & 15, kgrp = lane >> 4;
  int slab = bxi >> 2;
  f32x4_t acc[4][4];
#pragma unroll
  for (int i = 0; i < 4; ++i)
#pragma unroll
    for (int j = 0; j < 4; ++j) acc[i][j] = (f32x4_t){0.f, 0.f, 0.f, 0.f};

  int perm = (((lane & 7) ^ (lane >> 3)) << 3);
  const unsigned short* Asrc = Ab + (long)(wave * 32 + (lane >> 3)) * 512 + perm;
  const unsigned short* Bsrc = Bb + (long)(wave * 32 + (lane >> 3)) * 512 + perm;
  int woff = wave * 4096;

  // prologue: stage tile 0 into buffer 0
#pragma unroll
  for (int i = 0; i < 4; ++i) {
    gload_lds16(Asrc + (long)i * 8 * 512, lds + woff + i * 1024);
    gload_lds16(Bsrc + (long)i * 8 * 512, lds + 16384 + woff + i * 1024);
  }
  __syncthreads();

  for (int kt = 0; kt < 8; ++kt) {
    char* cur = lds + ((kt & 1) << 15);
    char* nxt = lds + (((kt + 1) & 1) << 15);
    if (kt < 7) {  // stage next tile into the other buffer
#pragma unroll
      for (int i = 0; i < 4; ++i) {
        gload_lds16(Asrc + (long)i * 8 * 512 + (kt + 1) * 64,
                    nxt + woff + i * 1024);
        gload_lds16(Bsrc + (long)i * 8 * 512 + (kt + 1) * 64,
                    nxt + 16384 + woff + i * 1024);
      }
    }
#pragma unroll
    for (int ks = 0; ks < 2; ++ks) {
      bf16x8_t af[4], bfv[4];
#pragma unroll
      for (int mi = 0; mi < 4; ++mi) {
        int r = wr * 64 + mi * 16 + lrow;
        int o = r * 128 + ks * 64 + kgrp * 16;
        o ^= (r & 7) << 4;
        af[mi] = *(bf16x8_t*)(cur + o);
      }
#pragma unroll
      for (int ni = 0; ni < 4; ++ni) {
        int r = wc * 64 + ni * 16 + lrow;
        int o = r * 128 + ks * 64 + kgrp * 16;
        o ^= (r & 7) << 4;
        bfv[ni] = *(bf16x8_t*)(cur + 16384 + o);
      }
      if (slab < 2) {  // wave-uniform branch
#pragma unroll
        for (int mi = 0; mi < 4; ++mi)
#pragma unroll
          for (int ni = 0; ni < 4; ++ni)
            acc[mi][ni] = mfma16(af[mi], bfv[ni], acc[mi][ni]);
      } else {
#pragma unroll
        for (int ni = 0; ni < 4; ++ni)
#pragma unroll
          for (int mi = 0; mi < 4; ++mi)
            acc[ni][mi] = mfma16(bfv[ni], af[mi], acc[ni][mi]);  // transposed
      }
    }
    __syncthreads();  // next tile staged + all reads of cur done
  }

  if (slab < 2) {
    const float* bias = slab == 0 ? qb : kb;
    float scl = slab == 0 ? scale : 1.f;
    int rowloc = (bxi & 3) * 128 + wr * 64;  // c within slab
    int colbase = byi * 128 + wc * 64;       // n
    unsigned short* ob = (slab == 0 ? Q2 : K2) + ((long)bz << 19);
#pragma unroll
    for (int mi = 0; mi < 4; ++mi) {
#pragma unroll
      for (int ni = 0; ni < 4; ++ni) {
        int row0 = rowloc + mi * 16 + kgrp * 4;
        int col = colbase + ni * 16 + lrow;
        unsigned short us[4];
#pragma unroll
        for (int rg = 0; rg < 4; ++rg)
          us[rg] = f2bf((acc[mi][ni][rg] + bias[row0 + rg]) * scl);
        long off = ((long)(col >> 4) << 13) + ((long)(row0 >> 3) << 7) +
                   ((col & 15) << 3) + (row0 & 7);
        *(ushort4*)(ob + off) = make_ushort4(us[0], us[1], us[2], us[3]);
      }
    }
  } else {
    int cbase = (bxi & 3) * 128 + wr * 64;  // c
    int nbase = byi * 128 + wc * 64;        // n
    unsigned short* ob = V2 + ((long)bz << 19);
#pragma unroll
    for (int ni = 0; ni < 4; ++ni) {
#pragma unroll
      for (int mi = 0; mi < 4; ++mi) {
        int n0 = nbase + ni * 16 + kgrp * 4;
        int c = cbase + mi * 16 + lrow;
        float bv = vb[c];
        unsigned short us[4];
#pragma unroll
        for (int rg = 0; rg < 4; ++rg) us[rg] = f2bf(acc[ni][mi][rg] + bv);
        long off = ((long)(c >> 4) << 14) + ((long)(n0 >> 3) << 7) +
                   ((c & 15) << 3) + (n0 & 7);
        *(ushort4*)(ob + off) = make_ushort4(us[0], us[1], us[2], us[3]);
      }
    }
  }
}

// ---------------------------------------------------------------- fused attn+PV
// 256 blocks x 512 threads (8 waves, 2/SIMD); b = f&15 pins batch to XCD b%8.
// Q LDS-staged into P2 region; K direct frag-blocked 1KB wave loads; P2
// (128KB) overlays Q after a barrier. No softmax max-subtraction (scores
// ~N(0,1.44) in exp2 domain -> huge headroom; p/sum identical). Transposed
// QK^T (mfma(kf,qa)) -> ushort4 P stores + 2-stage sum reduce.
__global__ __launch_bounds__(512, 1) void attn_pv_k(
    const unsigned short* __restrict__ q2, const unsigned short* __restrict__ k2,
    const unsigned short* __restrict__ v2, unsigned short* __restrict__ ao) {
  int f = blockIdx.x;
  int b = f & 15, ib = f >> 4;  // rows ib*64..+64
  int tid = threadIdx.x, lane = tid & 63, wave = tid >> 6;  // 8 waves
  int lrow = lane & 15, kgrp = lane >> 4;
  __shared__ unsigned short P2[65536];  // 128KB; first 64KB doubles as Q stage
  __shared__ float red1[8][64];
  __shared__ float invr[64];
  // ---- stage Q: 64KB contiguous -> P2[0..32768) linear ----
  {
    const unsigned short* qsrc =
        q2 + ((long)b << 19) + ((long)(ib * 4) << 13) + wave * 4096 + lane * 8;
    char* qdst = (char*)P2 + wave * 8192;
#pragma unroll
    for (int i = 0; i < 8; ++i) gload_lds16(qsrc + i * 512, qdst + i * 1024);
  }
  asm volatile("s_waitcnt vmcnt(0)" ::: "memory");
  __syncthreads();
  f32x4_t acc[4][8];
#pragma unroll
  for (int h = 0; h < 4; ++h)
#pragma unroll
    for (int t = 0; t < 8; ++t) acc[h][t] = (f32x4_t){0.f, 0.f, 0.f, 0.f};
  const unsigned short* kb =
      k2 + ((long)b << 19) + ((long)(wave * 8) << 13) + lane * 8;
  for (int ks = 0; ks < 16; ++ks) {  // K = 512
    bf16x8_t kf[8];
#pragma unroll
    for (int t = 0; t < 8; ++t)
      kf[t] = *(const bf16x8_t*)(kb + t * 8192 + ks * 512);
    bf16x8_t qa[4];
#pragma unroll
    for (int h = 0; h < 4; ++h)
      qa[h] = *(const bf16x8_t*)&P2[h * 8192 + ks * 512 + lane * 8];
    __builtin_amdgcn_s_setprio(1);
#pragma unroll
    for (int h = 0; h < 4; ++h)
#pragma unroll
      for (int t = 0; t < 8; ++t) acc[h][t] = mfma16(kf[t], qa[h], acc[h][t]);
    __builtin_amdgcn_s_setprio(0);
  }
  // acc[h][t][rg] = score[j = wave*128 + t*16 + kgrp*4 + rg][i = h*16 + lrow]
  __syncthreads();  // all waves past K-loop: Q dead, P2 region writable
  // ---- exp2 (no max subtraction) + vectorized P stage + row sums ----
  float sm[4] = {0.f, 0.f, 0.f, 0.f};
#pragma unroll
  for (int h = 0; h < 4; ++h) {
#pragma unroll
    for (int t = 0; t < 8; ++t) {
      int jb = wave * 16 + t * 2 + (kgrp >> 1);
      int off = h * 16384 + jb * 128 + (((lrow ^ (jb & 7)) << 3) | ((kgrp & 1) << 2));
      unsigned short us[4];
#pragma unroll
      for (int rg = 0; rg < 4; ++rg) {
        float p = exp2f(acc[h][t][rg]);  // scores already in log2 domain
        sm[h] += p;
        us[rg] = f2bf(p);
      }
      *(ushort4*)&P2[off] = make_ushort4(us[0], us[1], us[2], us[3]);
    }
  }
#pragma unroll
  for (int m = 16; m < 64; m <<= 1)
#pragma unroll
    for (int h = 0; h < 4; ++h) sm[h] += __shfl_xor(sm[h], m);
  if (kgrp == 0) {
#pragma unroll
    for (int h = 0; h < 4; ++h) red1[wave][h * 16 + lrow] = sm[h];
  }
  __syncthreads();  // P2 + red1 complete
  if (tid < 64) {
    float s = red1[0][tid];
#pragma unroll
    for (int w = 1; w < 8; ++w) s += red1[w][tid];
    invr[tid] = 1.f / s;
  }
  __syncthreads();
  // ---- PV: wave owns channels [wave*64, +64), 2-deep V prefetch ----
  f32x4_t o[4][4];
#pragma unroll
  for (int h = 0; h < 4; ++h)
#pragma unroll
    for (int cf = 0; cf < 4; ++cf) o[h][cf] = (f32x4_t){0.f, 0.f, 0.f, 0.f};
  const char* vb2 =
      (const char*)(v2 + ((long)b << 19) + ((long)(wave * 4) << 14)) + lane * 16;
  bf16x8_t vc[4];
#pragma unroll
  for (int cf = 0; cf < 4; ++cf) vc[cf] = *(const bf16x8_t*)(vb2 + cf * 32768);
#pragma unroll
  for (int js = 0; js < 32; ++js) {
    bf16x8_t vn[4];
    if (js < 31) {
#pragma unroll
      for (int cf = 0; cf < 4; ++cf)
        vn[cf] = *(const bf16x8_t*)(vb2 + cf * 32768 + (js + 1) * 1024);
    }
    int jb = js * 4 + kgrp;
    int pox = ((lrow ^ (jb & 7)) << 3) + jb * 128;
    bf16x8_t pa[4];
#pragma unroll
    for (int h = 0; h < 4; ++h)
      pa[h] = *(const bf16x8_t*)&P2[h * 16384 + pox];
    __builtin_amdgcn_s_setprio(1);
#pragma unroll
    for (int h = 0; h < 4; ++h)
#pragma unroll
      for (int cf = 0; cf < 4; ++cf)
        o[h][cf] = mfma16(pa[h], vc[cf], o[h][cf]);
    __builtin_amdgcn_s_setprio(0);
    if (js < 31) {
#pragma unroll
      for (int cf = 0; cf < 4; ++cf) vc[cf] = vn[cf];
    }
  }
  float inv[4][4];
#pragma unroll
  for (int h = 0; h < 4; ++h)
#pragma unroll
    for (int rg = 0; rg < 4; ++rg)
      inv[h][rg] = invr[h * 16 + kgrp * 4 + rg];
  unsigned short* aob = ao + ((long)(b * N_ + ib * 64)) * C_;
#pragma unroll
  for (int h = 0; h < 4; ++h)
#pragma unroll
    for (int cf = 0; cf < 4; ++cf) {
      int c = wave * 64 + cf * 16 + lrow;
#pragma unroll
      for (int rg = 0; rg < 4; ++rg) {
        int i = h * 16 + kgrp * 4 + rg;
        aob[(long)i * C_ + c] = f2bf(o[h][cf][rg] * inv[h][rg]);
      }
    }
}

// ---------------------------------------------------------------- proj GEMM
// out = x + Wp*AO^T + pb (fp32, (b,c,n)); A=Wp (512x512), B=AO (b,n,c).
__global__ __launch_bounds__(256) void gemm_proj(
    const unsigned short* __restrict__ A, const unsigned short* __restrict__ Bm,
    const float* __restrict__ bias, const float* __restrict__ resid,
    float* __restrict__ outp) {
  int flat = blockIdx.x + 4 * (blockIdx.y + 8 * blockIdx.z);  // 512 = 8*64
  int nf = (flat & 7) * 64 + (flat >> 3);
  int bxi = nf & 3, byi = (nf >> 2) & 7, bz = nf >> 5;
  const unsigned short* Ab = A + (long)bxi * 128 * 512;
  const unsigned short* Bb = Bm + (long)bz * N_ * C_ + (long)byi * 128 * 512;
  __shared__ char lds[32768];
  char* As = lds;
  char* Bs = lds + 16384;
  int tid = threadIdx.x;
  int lane = tid & 63, wave = tid >> 6;
  int wr = wave >> 1, wc = wave & 1;
  int lrow = lane & 15, kgrp = lane >> 4;
  f32x4_t acc[4][4];
#pragma unroll
  for (int i = 0; i < 4; ++i)
#pragma unroll
    for (int j = 0; j < 4; ++j) acc[i][j] = (f32x4_t){0.f, 0.f, 0.f, 0.f};

  int perm = (((lane & 7) ^ (lane >> 3)) << 3);
  const unsigned short* Asrc = Ab + (long)(wave * 32 + (lane >> 3)) * 512 + perm;
  const unsigned short* Bsrc = Bb + (long)(wave * 32 + (lane >> 3)) * 512 + perm;
  char* Adst = As + wave * 32 * 128;
  char* Bdst = Bs + wave * 32 * 128;

  for (int kt = 0; kt < 8; ++kt) {
    __syncthreads();
#pragma unroll
    for (int i = 0; i < 4; ++i) {
      gload_lds16(Asrc + (long)i * 8 * 512 + kt * 64, Adst + i * 1024);
      gload_lds16(Bsrc + (long)i * 8 * 512 + kt * 64, Bdst + i * 1024);
    }
    __syncthreads();
#pragma unroll
    for (int ks = 0; ks < 2; ++ks) {
      bf16x8_t af[4], bfv[4];
#pragma unroll
      for (int mi = 0; mi < 4; ++mi) {
        int r = wr * 64 + mi * 16 + lrow;
        int o = r * 128 + ks * 64 + kgrp * 16;
        o ^= (r & 7) << 4;
        af[mi] = *(bf16x8_t*)(As + o);
      }
#pragma unroll
      for (int ni = 0; ni < 4; ++ni) {
        int r = wc * 64 + ni * 16 + lrow;
        int o = r * 128 + ks * 64 + kgrp * 16;
        o ^= (r & 7) << 4;
        bfv[ni] = *(bf16x8_t*)(Bs + o);
      }
#pragma unroll
      for (int mi = 0; mi < 4; ++mi)
#pragma unroll
        for (int ni = 0; ni < 4; ++ni)
          acc[mi][ni] = mfma16(af[mi], bfv[ni], acc[mi][ni]);
    }
  }

  int rowbase = bxi * 128 + wr * 64;
  int colbase = byi * 128 + wc * 64;
  float* ob = outp + (long)bz * C_ * N_;
  const float* rb = resid + (long)bz * C_ * N_;
#pragma unroll
  for (int mi = 0; mi < 4; ++mi) {
#pragma unroll
    for (int ni = 0; ni < 4; ++ni) {
      int row0 = rowbase + mi * 16 + kgrp * 4;
      int col = colbase + ni * 16 + lrow;
#pragma unroll
      for (int rg = 0; rg < 4; ++rg) {
        int r = row0 + rg;
        ob[(long)r * N_ + col] =
            acc[mi][ni][rg] + bias[r] + rb[(long)r * N_ + col];
      }
    }
  }
}

// ---------------------------------------------------------------- launch
extern "C" void kernel_launch(void* const* d_in, const int* in_sizes, int n_in,
                              void* d_out, int out_size, void* d_ws,
                              size_t ws_size, hipStream_t stream) {
  (void)in_sizes; (void)n_in; (void)out_size; (void)ws_size;
  const float* x = (const float*)d_in[0];
  const float* nw = (const float*)d_in[1];
  const float* nb = (const float*)d_in[2];
  const float* qw = (const float*)d_in[3];
  const float* qbias = (const float*)d_in[4];
  const float* kw = (const float*)d_in[5];
  const float* kbias = (const float*)d_in[6];
  const float* vw = (const float*)d_in[7];
  const float* vbias = (const float*)d_in[8];
  const float* pw = (const float*)d_in[9];
  const float* pbias = (const float*)d_in[10];
  float* out = (float*)d_out;

  char* ws = (char*)d_ws;
  unsigned short* WQKV = (unsigned short*)(ws + 0);        // 3MB stacked linear
  unsigned short* Wp = (unsigned short*)(ws + 3145728);    // 0.5MB
  unsigned short* HN = (unsigned short*)(ws + 4194304);    // 16MB (b,n,c)
  unsigned short* Q2 = (unsigned short*)(ws + 20971520);   // 16MB frag [n/16][c/8]
  unsigned short* K2 = (unsigned short*)(ws + 37748736);   // 16MB frag [n/16][c/8]
  unsigned short* V2 = (unsigned short*)(ws + 54525952);   // 16MB frag [c/16][n/8]
  unsigned short* AO = (unsigned short*)(ws + 71303168);   // 16MB (b,n,c)

  castw_k<<<256, 256, 0, stream>>>(qw, kw, vw, pw, WQKV, Wp);
  gn_fused_k<<<256, 512, 0, stream>>>(x, nw, nb, HN);

  // 512^-0.5 * log2(e): scores land in the exp2 domain for native exp2f
  const float scale = 0.06375871512f;
  // q,k,v in one dispatch (A+B double-buffered LDS, 1 barrier/kt)
  gemm_qkv<<<dim3(12, 8, B_), 256, 0, stream>>>(WQKV, HN, qbias, kbias, vbias,
                                                Q2, K2, V2, scale);
  // fused QK^T + softmax + PV -> AO (b,n,c)
  attn_pv_k<<<256, 512, 0, stream>>>(Q2, K2, V2, AO);
  // out = x + Wp*AO^T + pb (fp32, (b,c,n))
  gemm_proj<<<dim3(4, 8, B_), 256, 0, stream>>>(Wp, AO, pbias, x, out);
}

// Round 19
// 108.557 us; speedup vs baseline: 1.1806x; 1.0220x over previous
//
#include <hip/hip_runtime.h>

#define B_ 16
#define C_ 512
#define N_ 1024

typedef __attribute__((ext_vector_type(8))) short bf16x8_t;
typedef __attribute__((ext_vector_type(4))) float f32x4_t;

__device__ __forceinline__ unsigned short f2bf(float f) {
  unsigned int u = __float_as_uint(f);
  u += 0x7fffu + ((u >> 16) & 1u);
  return (unsigned short)(u >> 16);
}

__device__ __forceinline__ f32x4_t mfma16(bf16x8_t a, bf16x8_t b, f32x4_t c) {
  return __builtin_amdgcn_mfma_f32_16x16x32_bf16(a, b, c, 0, 0, 0);
}

// async global->LDS, 16B per lane; dest is wave-uniform base (lane*16 added by HW)
__device__ __forceinline__ void gload_lds16(const void* g, void* l) {
  __builtin_amdgcn_global_load_lds(
      (const __attribute__((address_space(1))) unsigned int*)g,
      (__attribute__((address_space(3))) unsigned int*)l, 16, 0, 0);
}

// ---------------------------------------------------------------- weights cast
// Vectorized (float4 in, ushort4 out). Stacks Wq|Wk|Wv for the fused qkv GEMM.
__global__ __launch_bounds__(256) void castw_k(
    const float* __restrict__ qw, const float* __restrict__ kw,
    const float* __restrict__ vw, const float* __restrict__ pw,
    unsigned short* __restrict__ Wqkv, unsigned short* __restrict__ Wp) {
  int i = (blockIdx.x * 256 + threadIdx.x) * 4;  // 262144 elements each
  float4 a = *(const float4*)(qw + i);
  float4 b = *(const float4*)(kw + i);
  float4 c = *(const float4*)(vw + i);
  float4 d = *(const float4*)(pw + i);
  *(ushort4*)(Wqkv + i) = make_ushort4(f2bf(a.x), f2bf(a.y), f2bf(a.z), f2bf(a.w));
  *(ushort4*)(Wqkv + 262144 + i) =
      make_ushort4(f2bf(b.x), f2bf(b.y), f2bf(b.z), f2bf(b.w));
  *(ushort4*)(Wqkv + 524288 + i) =
      make_ushort4(f2bf(c.x), f2bf(c.y), f2bf(c.z), f2bf(c.w));
  *(ushort4*)(Wp + i) = make_ushort4(f2bf(d.x), f2bf(d.y), f2bf(d.z), f2bf(d.w));
}

// ---------------------------------------------------------------- fused GN
__global__ __launch_bounds__(512, 1) void gn_fused_k(
    const float* __restrict__ x, const float* __restrict__ gw,
    const float* __restrict__ gb, unsigned short* __restrict__ hn) {
  int blk = blockIdx.x;
  int b = blk >> 4, gp = blk & 15;
  int t = threadIdx.x, lane = t & 63, wave = t >> 6;
  __shared__ float xs[32768];      // [c][n ^ (((c>>3)&3)<<4)] = 128KB
  __shared__ float red[2][2][8];   // [sum/sq][group][wave]
  const float* xg = x + ((long)b * C_ + gp * 32) * N_;  // 128KB contiguous
  float s0 = 0.f, s20 = 0.f, s1 = 0.f, s21 = 0.f;
#pragma unroll
  for (int i = 0; i < 16; ++i) {
    int f4 = t + 512 * i;
    float4 v = ((const float4*)xg)[f4];
    float sum = v.x + v.y + v.z + v.w;
    float sq = v.x * v.x + v.y * v.y + v.z * v.z + v.w * v.w;
    if (i < 8) { s0 += sum; s20 += sq; } else { s1 += sum; s21 += sq; }
    int fi = f4 << 2;
    int c = fi >> 10, n = fi & 1023;
    int nx = n ^ (((c >> 3) & 3) << 4);
    *(float4*)&xs[(c << 10) + nx] = v;
  }
#pragma unroll
  for (int m = 1; m < 64; m <<= 1) {
    s0 += __shfl_xor(s0, m); s20 += __shfl_xor(s20, m);
    s1 += __shfl_xor(s1, m); s21 += __shfl_xor(s21, m);
  }
  if (lane == 0) {
    red[0][0][wave] = s0; red[1][0][wave] = s20;
    red[0][1][wave] = s1; red[1][1][wave] = s21;
  }
  __syncthreads();
  float m0 = 0.f, v0 = 0.f, m1 = 0.f, v1 = 0.f;
#pragma unroll
  for (int w = 0; w < 8; ++w) {
    m0 += red[0][0][w]; v0 += red[1][0][w];
    m1 += red[0][1][w]; v1 += red[1][1][w];
  }
  m0 *= (1.f / 16384.f); m1 *= (1.f / 16384.f);
  float rv0 = rsqrtf(v0 * (1.f / 16384.f) - m0 * m0 + 1e-5f);
  float rv1 = rsqrtf(v1 * (1.f / 16384.f) - m1 * m1 + 1e-5f);
  int q = t & 3;
  float mean = (q >> 1) ? m1 : m0, rv = (q >> 1) ? rv1 : rv0;
  float ga[8], be[8];
#pragma unroll
  for (int jj = 0; jj < 8; ++jj) {
    int gc = gp * 32 + q * 8 + jj;
    ga[jj] = gw[gc] * rv;
    be[jj] = gb[gc] - mean * ga[jj];
  }
  unsigned short* ob = hn + (long)b * N_ * C_ + gp * 32 + q * 8;
  int n0 = t >> 2;  // 0..127
  for (int it = 0; it < 8; ++it) {
    int n = n0 + (it << 7);
    int nsw = n ^ (q << 4);
    unsigned short us[8];
#pragma unroll
    for (int jj = 0; jj < 8; ++jj) {
      int c = q * 8 + jj;
      us[jj] = f2bf(xs[(c << 10) + nsw] * ga[jj] + be[jj]);
    }
    *(uint4*)(ob + (long)n * C_) = *(uint4*)us;
  }
}

// ---------------------------------------------------------------- QKV GEMM
// r14 champion form: merged single dispatch, 32KB single-buffered LDS,
// 2 barriers/kt (occupancy-optimal for this shape — dbuf variants measured
// worse). Epilogue per 512-row slab: 0 -> Q2 (*scale), 1 -> K2 frag-blocked
// ushort4; 2 -> V2 [c/16][n/8][c%16][n%8] scalar stores.
__global__ __launch_bounds__(256) void gemm_qkv(
    const unsigned short* __restrict__ W, const unsigned short* __restrict__ HN,
    const float* __restrict__ qb, const float* __restrict__ kb,
    const float* __restrict__ vb, unsigned short* __restrict__ Q2,
    unsigned short* __restrict__ K2, unsigned short* __restrict__ V2,
    float scale) {
  int flat = blockIdx.x + 12 * (blockIdx.y + 8 * blockIdx.z);  // 1536 = 8*192
  int nf = (flat & 7) * 192 + (flat >> 3);
  int bxi = nf % 12, rem = nf / 12;
  int byi = rem & 7, bz = rem >> 3;
  const unsigned short* Ab = W + (long)bxi * 128 * 512;
  const unsigned short* Bb = HN + (long)bz * N_ * C_ + (long)byi * 128 * 512;
  __shared__ char lds[32768];
  char* As = lds;
  char* Bs = lds + 16384;
  int tid = threadIdx.x;
  int lane = tid & 63, wave = tid >> 6;
  int wr = wave >> 1, wc = wave & 1;
  int lrow = lane & 15, kgrp = lane >> 4;
  f32x4_t acc[4][4];
#pragma unroll
  for (int i = 0; i < 4; ++i)
#pragma unroll
    for (int j = 0; j < 4; ++j) acc[i][j] = (f32x4_t){0.f, 0.f, 0.f, 0.f};

  int perm = (((lane & 7) ^ (lane >> 3)) << 3);
  const unsigned short* Asrc = Ab + (long)(wave * 32 + (lane >> 3)) * 512 + perm;
  const unsigned short* Bsrc = Bb + (long)(wave * 32 + (lane >> 3)) * 512 + perm;
  char* Adst = As + wave * 32 * 128;
  char* Bdst = Bs + wave * 32 * 128;

  for (int kt = 0; kt < 8; ++kt) {
    __syncthreads();
#pragma unroll
    for (int i = 0; i < 4; ++i) {
      gload_lds16(Asrc + (long)i * 8 * 512 + kt * 64, Adst + i * 1024);
      gload_lds16(Bsrc + (long)i * 8 * 512 + kt * 64, Bdst + i * 1024);
    }
    __syncthreads();
#pragma unroll
    for (int ks = 0; ks < 2; ++ks) {
      bf16x8_t af[4], bfv[4];
#pragma unroll
      for (int mi = 0; mi < 4; ++mi) {
        int r = wr * 64 + mi * 16 + lrow;
        int o = r * 128 + ks * 64 + kgrp * 16;
        o ^= (r & 7) << 4;
        af[mi] = *(bf16x8_t*)(As + o);
      }
#pragma unroll
      for (int ni = 0; ni < 4; ++ni) {
        int r = wc * 64 + ni * 16 + lrow;
        int o = r * 128 + ks * 64 + kgrp * 16;
        o ^= (r & 7) << 4;
        bfv[ni] = *(bf16x8_t*)(Bs + o);
      }
#pragma unroll
      for (int mi = 0; mi < 4; ++mi)
#pragma unroll
        for (int ni = 0; ni < 4; ++ni)
          acc[mi][ni] = mfma16(af[mi], bfv[ni], acc[mi][ni]);
    }
  }

  int slab = bxi >> 2;
  const float* bias = slab == 0 ? qb : (slab == 1 ? kb : vb);
  float scl = slab == 0 ? scale : 1.f;
  int rowloc = (bxi & 3) * 128 + wr * 64;  // c within slab
  int colbase = byi * 128 + wc * 64;       // n
  unsigned short* ob =
      (slab == 0 ? Q2 : (slab == 1 ? K2 : V2)) + ((long)bz << 19);
#pragma unroll
  for (int mi = 0; mi < 4; ++mi) {
#pragma unroll
    for (int ni = 0; ni < 4; ++ni) {
      int row0 = rowloc + mi * 16 + kgrp * 4;
      int col = colbase + ni * 16 + lrow;
      unsigned short us[4];
#pragma unroll
      for (int rg = 0; rg < 4; ++rg)
        us[rg] = f2bf((acc[mi][ni][rg] + bias[row0 + rg]) * scl);
      if (slab < 2) {
        long off = ((long)(col >> 4) << 13) + ((long)(row0 >> 3) << 7) +
                   ((col & 15) << 3) + (row0 & 7);
        *(ushort4*)(ob + off) = make_ushort4(us[0], us[1], us[2], us[3]);
      } else {
        long base16 = ((long)(row0 >> 4) << 14) + ((long)(col >> 3) << 7) +
                      (col & 7) + (row0 & 15) * 8;
#pragma unroll
        for (int rg = 0; rg < 4; ++rg) ob[base16 + rg * 8] = us[rg];
      }
    }
  }
}

// ---------------------------------------------------------------- fused attn+PV
// 256 blocks x 512 threads (8 waves, 2/SIMD); b = f&15 pins batch to XCD b%8.
// Q LDS-staged into P2 region; K direct frag-blocked 1KB wave loads; P2
// (128KB) overlays Q after a barrier. No softmax max-subtraction (scores
// ~N(0,1.44) in exp2 domain -> huge headroom; p/sum identical). Transposed
// QK^T (mfma(kf,qa)) -> ushort4 P stores + 2-stage sum reduce.
__global__ __launch_bounds__(512, 1) void attn_pv_k(
    const unsigned short* __restrict__ q2, const unsigned short* __restrict__ k2,
    const unsigned short* __restrict__ v2, unsigned short* __restrict__ ao) {
  int f = blockIdx.x;
  int b = f & 15, ib = f >> 4;  // rows ib*64..+64
  int tid = threadIdx.x, lane = tid & 63, wave = tid >> 6;  // 8 waves
  int lrow = lane & 15, kgrp = lane >> 4;
  __shared__ unsigned short P2[65536];  // 128KB; first 64KB doubles as Q stage
  __shared__ float red1[8][64];
  __shared__ float invr[64];
  // ---- stage Q: 64KB contiguous -> P2[0..32768) linear ----
  {
    const unsigned short* qsrc =
        q2 + ((long)b << 19) + ((long)(ib * 4) << 13) + wave * 4096 + lane * 8;
    char* qdst = (char*)P2 + wave * 8192;
#pragma unroll
    for (int i = 0; i < 8; ++i) gload_lds16(qsrc + i * 512, qdst + i * 1024);
  }
  asm volatile("s_waitcnt vmcnt(0)" ::: "memory");
  __syncthreads();
  f32x4_t acc[4][8];
#pragma unroll
  for (int h = 0; h < 4; ++h)
#pragma unroll
    for (int t = 0; t < 8; ++t) acc[h][t] = (f32x4_t){0.f, 0.f, 0.f, 0.f};
  const unsigned short* kb =
      k2 + ((long)b << 19) + ((long)(wave * 8) << 13) + lane * 8;
  for (int ks = 0; ks < 16; ++ks) {  // K = 512
    bf16x8_t kf[8];
#pragma unroll
    for (int t = 0; t < 8; ++t)
      kf[t] = *(const bf16x8_t*)(kb + t * 8192 + ks * 512);
    bf16x8_t qa[4];
#pragma unroll
    for (int h = 0; h < 4; ++h)
      qa[h] = *(const bf16x8_t*)&P2[h * 8192 + ks * 512 + lane * 8];
    __builtin_amdgcn_s_setprio(1);
#pragma unroll
    for (int h = 0; h < 4; ++h)
#pragma unroll
      for (int t = 0; t < 8; ++t) acc[h][t] = mfma16(kf[t], qa[h], acc[h][t]);
    __builtin_amdgcn_s_setprio(0);
  }
  // acc[h][t][rg] = score[j = wave*128 + t*16 + kgrp*4 + rg][i = h*16 + lrow]
  __syncthreads();  // all waves past K-loop: Q dead, P2 region writable
  // ---- exp2 (no max subtraction) + vectorized P stage + row sums ----
  float sm[4] = {0.f, 0.f, 0.f, 0.f};
#pragma unroll
  for (int h = 0; h < 4; ++h) {
#pragma unroll
    for (int t = 0; t < 8; ++t) {
      int jb = wave * 16 + t * 2 + (kgrp >> 1);
      int off = h * 16384 + jb * 128 + (((lrow ^ (jb & 7)) << 3) | ((kgrp & 1) << 2));
      unsigned short us[4];
#pragma unroll
      for (int rg = 0; rg < 4; ++rg) {
        float p = exp2f(acc[h][t][rg]);  // scores already in log2 domain
        sm[h] += p;
        us[rg] = f2bf(p);
      }
      *(ushort4*)&P2[off] = make_ushort4(us[0], us[1], us[2], us[3]);
    }
  }
#pragma unroll
  for (int m = 16; m < 64; m <<= 1)
#pragma unroll
    for (int h = 0; h < 4; ++h) sm[h] += __shfl_xor(sm[h], m);
  if (kgrp == 0) {
#pragma unroll
    for (int h = 0; h < 4; ++h) red1[wave][h * 16 + lrow] = sm[h];
  }
  __syncthreads();  // P2 + red1 complete
  if (tid < 64) {
    float s = red1[0][tid];
#pragma unroll
    for (int w = 1; w < 8; ++w) s += red1[w][tid];
    invr[tid] = 1.f / s;
  }
  __syncthreads();
  // ---- PV: wave owns channels [wave*64, +64), 2-deep V prefetch ----
  f32x4_t o[4][4];
#pragma unroll
  for (int h = 0; h < 4; ++h)
#pragma unroll
    for (int cf = 0; cf < 4; ++cf) o[h][cf] = (f32x4_t){0.f, 0.f, 0.f, 0.f};
  const char* vb2 =
      (const char*)(v2 + ((long)b << 19) + ((long)(wave * 4) << 14)) + lane * 16;
  bf16x8_t vc[4];
#pragma unroll
  for (int cf = 0; cf < 4; ++cf) vc[cf] = *(const bf16x8_t*)(vb2 + cf * 32768);
#pragma unroll
  for (int js = 0; js < 32; ++js) {
    bf16x8_t vn[4];
    if (js < 31) {
#pragma unroll
      for (int cf = 0; cf < 4; ++cf)
        vn[cf] = *(const bf16x8_t*)(vb2 + cf * 32768 + (js + 1) * 1024);
    }
    int jb = js * 4 + kgrp;
    int pox = ((lrow ^ (jb & 7)) << 3) + jb * 128;
    bf16x8_t pa[4];
#pragma unroll
    for (int h = 0; h < 4; ++h)
      pa[h] = *(const bf16x8_t*)&P2[h * 16384 + pox];
    __builtin_amdgcn_s_setprio(1);
#pragma unroll
    for (int h = 0; h < 4; ++h)
#pragma unroll
      for (int cf = 0; cf < 4; ++cf)
        o[h][cf] = mfma16(pa[h], vc[cf], o[h][cf]);
    __builtin_amdgcn_s_setprio(0);
    if (js < 31) {
#pragma unroll
      for (int cf = 0; cf < 4; ++cf) vc[cf] = vn[cf];
    }
  }
  float inv[4][4];
#pragma unroll
  for (int h = 0; h < 4; ++h)
#pragma unroll
    for (int rg = 0; rg < 4; ++rg)
      inv[h][rg] = invr[h * 16 + kgrp * 4 + rg];
  unsigned short* aob = ao + ((long)(b * N_ + ib * 64)) * C_;
#pragma unroll
  for (int h = 0; h < 4; ++h)
#pragma unroll
    for (int cf = 0; cf < 4; ++cf) {
      int c = wave * 64 + cf * 16 + lrow;
#pragma unroll
      for (int rg = 0; rg < 4; ++rg) {
        int i = h * 16 + kgrp * 4 + rg;
        aob[(long)i * C_ + c] = f2bf(o[h][cf][rg] * inv[h][rg]);
      }
    }
}

// ---------------------------------------------------------------- proj GEMM
// out = x + Wp*AO^T + pb (fp32, (b,c,n)); A=Wp (512x512), B=AO (b,n,c).
__global__ __launch_bounds__(256) void gemm_proj(
    const unsigned short* __restrict__ A, const unsigned short* __restrict__ Bm,
    const float* __restrict__ bias, const float* __restrict__ resid,
    float* __restrict__ outp) {
  int flat = blockIdx.x + 4 * (blockIdx.y + 8 * blockIdx.z);  // 512 = 8*64
  int nf = (flat & 7) * 64 + (flat >> 3);
  int bxi = nf & 3, byi = (nf >> 2) & 7, bz = nf >> 5;
  const unsigned short* Ab = A + (long)bxi * 128 * 512;
  const unsigned short* Bb = Bm + (long)bz * N_ * C_ + (long)byi * 128 * 512;
  __shared__ char lds[32768];
  char* As = lds;
  char* Bs = lds + 16384;
  int tid = threadIdx.x;
  int lane = tid & 63, wave = tid >> 6;
  int wr = wave >> 1, wc = wave & 1;
  int lrow = lane & 15, kgrp = lane >> 4;
  f32x4_t acc[4][4];
#pragma unroll
  for (int i = 0; i < 4; ++i)
#pragma unroll
    for (int j = 0; j < 4; ++j) acc[i][j] = (f32x4_t){0.f, 0.f, 0.f, 0.f};

  int perm = (((lane & 7) ^ (lane >> 3)) << 3);
  const unsigned short* Asrc = Ab + (long)(wave * 32 + (lane >> 3)) * 512 + perm;
  const unsigned short* Bsrc = Bb + (long)(wave * 32 + (lane >> 3)) * 512 + perm;
  char* Adst = As + wave * 32 * 128;
  char* Bdst = Bs + wave * 32 * 128;

  for (int kt = 0; kt < 8; ++kt) {
    __syncthreads();
#pragma unroll
    for (int i = 0; i < 4; ++i) {
      gload_lds16(Asrc + (long)i * 8 * 512 + kt * 64, Adst + i * 1024);
      gload_lds16(Bsrc + (long)i * 8 * 512 + kt * 64, Bdst + i * 1024);
    }
    __syncthreads();
#pragma unroll
    for (int ks = 0; ks < 2; ++ks) {
      bf16x8_t af[4], bfv[4];
#pragma unroll
      for (int mi = 0; mi < 4; ++mi) {
        int r = wr * 64 + mi * 16 + lrow;
        int o = r * 128 + ks * 64 + kgrp * 16;
        o ^= (r & 7) << 4;
        af[mi] = *(bf16x8_t*)(As + o);
      }
#pragma unroll
      for (int ni = 0; ni < 4; ++ni) {
        int r = wc * 64 + ni * 16 + lrow;
        int o = r * 128 + ks * 64 + kgrp * 16;
        o ^= (r & 7) << 4;
        bfv[ni] = *(bf16x8_t*)(Bs + o);
      }
#pragma unroll
      for (int mi = 0; mi < 4; ++mi)
#pragma unroll
        for (int ni = 0; ni < 4; ++ni)
          acc[mi][ni] = mfma16(af[mi], bfv[ni], acc[mi][ni]);
    }
  }

  int rowbase = bxi * 128 + wr * 64;
  int colbase = byi * 128 + wc * 64;
  float* ob = outp + (long)bz * C_ * N_;
  const float* rb = resid + (long)bz * C_ * N_;
#pragma unroll
  for (int mi = 0; mi < 4; ++mi) {
#pragma unroll
    for (int ni = 0; ni < 4; ++ni) {
      int row0 = rowbase + mi * 16 + kgrp * 4;
      int col = colbase + ni * 16 + lrow;
#pragma unroll
      for (int rg = 0; rg < 4; ++rg) {
        int r = row0 + rg;
        ob[(long)r * N_ + col] =
            acc[mi][ni][rg] + bias[r] + rb[(long)r * N_ + col];
      }
    }
  }
}

// ---------------------------------------------------------------- launch
extern "C" void kernel_launch(void* const* d_in, const int* in_sizes, int n_in,
                              void* d_out, int out_size, void* d_ws,
                              size_t ws_size, hipStream_t stream) {
  (void)in_sizes; (void)n_in; (void)out_size; (void)ws_size;
  const float* x = (const float*)d_in[0];
  const float* nw = (const float*)d_in[1];
  const float* nb = (const float*)d_in[2];
  const float* qw = (const float*)d_in[3];
  const float* qbias = (const float*)d_in[4];
  const float* kw = (const float*)d_in[5];
  const float* kbias = (const float*)d_in[6];
  const float* vw = (const float*)d_in[7];
  const float* vbias = (const float*)d_in[8];
  const float* pw = (const float*)d_in[9];
  const float* pbias = (const float*)d_in[10];
  float* out = (float*)d_out;

  char* ws = (char*)d_ws;
  unsigned short* WQKV = (unsigned short*)(ws + 0);        // 1.5MB stacked
  unsigned short* Wp = (unsigned short*)(ws + 1572864);    // 0.5MB
  unsigned short* HN = (unsigned short*)(ws + 2097152);    // 16MB (b,n,c)
  unsigned short* Q2 = (unsigned short*)(ws + 18874368);   // 16MB frag [n/16][c/8]
  unsigned short* K2 = (unsigned short*)(ws + 35651584);   // 16MB frag [n/16][c/8]
  unsigned short* V2 = (unsigned short*)(ws + 52428800);   // 16MB frag [c/16][n/8]
  unsigned short* AO = (unsigned short*)(ws + 69206016);   // 16MB (b,n,c)

  castw_k<<<256, 256, 0, stream>>>(qw, kw, vw, pw, WQKV, Wp);
  gn_fused_k<<<256, 512, 0, stream>>>(x, nw, nb, HN);

  // 512^-0.5 * log2(e): scores land in the exp2 domain for native exp2f
  const float scale = 0.06375871512f;
  // q,k,v in one dispatch
  gemm_qkv<<<dim3(12, 8, B_), 256, 0, stream>>>(WQKV, HN, qbias, kbias, vbias,
                                                Q2, K2, V2, scale);
  // fused QK^T + softmax + PV -> AO (b,n,c)
  attn_pv_k<<<256, 512, 0, stream>>>(Q2, K2, V2, AO);
  // out = x + Wp*AO^T + pb (fp32, (b,c,n))
  gemm_proj<<<dim3(4, 8, B_), 256, 0, stream>>>(Wp, AO, pbias, x, out);
}

// Round 20
// 102.114 us; speedup vs baseline: 1.2550x; 1.0631x over previous
//
#include <hip/hip_runtime.h>

#define B_ 16
#define C_ 512
#define N_ 1024

typedef __attribute__((ext_vector_type(8))) short bf16x8_t;
typedef __attribute__((ext_vector_type(4))) float f32x4_t;

__device__ __forceinline__ unsigned short f2bf(float f) {
  unsigned int u = __float_as_uint(f);
  u += 0x7fffu + ((u >> 16) & 1u);
  return (unsigned short)(u >> 16);
}

__device__ __forceinline__ f32x4_t mfma16(bf16x8_t a, bf16x8_t b, f32x4_t c) {
  return __builtin_amdgcn_mfma_f32_16x16x32_bf16(a, b, c, 0, 0, 0);
}

// async global->LDS, 16B per lane; dest is wave-uniform base (lane*16 added by HW)
__device__ __forceinline__ void gload_lds16(const void* g, void* l) {
  __builtin_amdgcn_global_load_lds(
      (const __attribute__((address_space(1))) unsigned int*)g,
      (__attribute__((address_space(3))) unsigned int*)l, 16, 0, 0);
}

// ---------------------------------------------------------------- weights cast
// Wq|Wk|Wv -> linear stacked (for qkv GEMM LDS staging).
// Wp -> FRAG-BLOCKED Wpf[c_out/16][c_in/8][c_out%16][c_in%8] so the fused
// attn+proj kernel loads A-fragments as contiguous 1KB wave loads from L2.
__global__ __launch_bounds__(256) void castw_k(
    const float* __restrict__ qw, const float* __restrict__ kw,
    const float* __restrict__ vw, const float* __restrict__ pw,
    unsigned short* __restrict__ Wqkv, unsigned short* __restrict__ Wpf) {
  int idx = blockIdx.x * 256 + threadIdx.x;  // grid 128 -> 32768 threads
  int m = idx >> 6;         // row 0..511
  int k0 = (idx & 63) * 8;  // k octet base
  long lin = (long)m * 512 + k0;
#pragma unroll
  for (int s = 0; s < 3; ++s) {
    const float* src = s == 0 ? qw : (s == 1 ? kw : vw);
    float4 a = *(const float4*)(src + lin);
    float4 b = *(const float4*)(src + lin + 4);
    unsigned short us[8] = {f2bf(a.x), f2bf(a.y), f2bf(a.z), f2bf(a.w),
                            f2bf(b.x), f2bf(b.y), f2bf(b.z), f2bf(b.w)};
    *(uint4*)(Wqkv + s * 262144 + lin) = *(uint4*)us;
  }
  float4 d = *(const float4*)(pw + lin);
  float4 d2 = *(const float4*)(pw + lin + 4);
  unsigned short up[8] = {f2bf(d.x),  f2bf(d.y),  f2bf(d.z),  f2bf(d.w),
                          f2bf(d2.x), f2bf(d2.y), f2bf(d2.z), f2bf(d2.w)};
  long fp = ((long)(m >> 4) << 13) + ((k0 >> 3) << 7) + ((m & 15) << 3);
  *(uint4*)(Wpf + fp) = *(uint4*)up;
}

// ---------------------------------------------------------------- fused GN
__global__ __launch_bounds__(512, 1) void gn_fused_k(
    const float* __restrict__ x, const float* __restrict__ gw,
    const float* __restrict__ gb, unsigned short* __restrict__ hn) {
  int blk = blockIdx.x;
  int b = blk >> 4, gp = blk & 15;
  int t = threadIdx.x, lane = t & 63, wave = t >> 6;
  __shared__ float xs[32768];      // [c][n ^ (((c>>3)&3)<<4)] = 128KB
  __shared__ float red[2][2][8];   // [sum/sq][group][wave]
  const float* xg = x + ((long)b * C_ + gp * 32) * N_;  // 128KB contiguous
  float s0 = 0.f, s20 = 0.f, s1 = 0.f, s21 = 0.f;
#pragma unroll
  for (int i = 0; i < 16; ++i) {
    int f4 = t + 512 * i;
    float4 v = ((const float4*)xg)[f4];
    float sum = v.x + v.y + v.z + v.w;
    float sq = v.x * v.x + v.y * v.y + v.z * v.z + v.w * v.w;
    if (i < 8) { s0 += sum; s20 += sq; } else { s1 += sum; s21 += sq; }
    int fi = f4 << 2;
    int c = fi >> 10, n = fi & 1023;
    int nx = n ^ (((c >> 3) & 3) << 4);
    *(float4*)&xs[(c << 10) + nx] = v;
  }
#pragma unroll
  for (int m = 1; m < 64; m <<= 1) {
    s0 += __shfl_xor(s0, m); s20 += __shfl_xor(s20, m);
    s1 += __shfl_xor(s1, m); s21 += __shfl_xor(s21, m);
  }
  if (lane == 0) {
    red[0][0][wave] = s0; red[1][0][wave] = s20;
    red[0][1][wave] = s1; red[1][1][wave] = s21;
  }
  __syncthreads();
  float m0 = 0.f, v0 = 0.f, m1 = 0.f, v1 = 0.f;
#pragma unroll
  for (int w = 0; w < 8; ++w) {
    m0 += red[0][0][w]; v0 += red[1][0][w];
    m1 += red[0][1][w]; v1 += red[1][1][w];
  }
  m0 *= (1.f / 16384.f); m1 *= (1.f / 16384.f);
  float rv0 = rsqrtf(v0 * (1.f / 16384.f) - m0 * m0 + 1e-5f);
  float rv1 = rsqrtf(v1 * (1.f / 16384.f) - m1 * m1 + 1e-5f);
  int q = t & 3;
  float mean = (q >> 1) ? m1 : m0, rv = (q >> 1) ? rv1 : rv0;
  float ga[8], be[8];
#pragma unroll
  for (int jj = 0; jj < 8; ++jj) {
    int gc = gp * 32 + q * 8 + jj;
    ga[jj] = gw[gc] * rv;
    be[jj] = gb[gc] - mean * ga[jj];
  }
  unsigned short* ob = hn + (long)b * N_ * C_ + gp * 32 + q * 8;
  int n0 = t >> 2;  // 0..127
  for (int it = 0; it < 8; ++it) {
    int n = n0 + (it << 7);
    int nsw = n ^ (q << 4);
    unsigned short us[8];
#pragma unroll
    for (int jj = 0; jj < 8; ++jj) {
      int c = q * 8 + jj;
      us[jj] = f2bf(xs[(c << 10) + nsw] * ga[jj] + be[jj]);
    }
    *(uint4*)(ob + (long)n * C_) = *(uint4*)us;
  }
}

// ---------------------------------------------------------------- QKV GEMM
// Champion form: merged single dispatch, 32KB single-buffered LDS, 2
// barriers/kt. Epilogue per 512-row slab: 0 -> Q2 (*scale), 1 -> K2
// frag-blocked ushort4; 2 -> V2 [c/16][n/8][c%16][n%8] scalar stores.
__global__ __launch_bounds__(256) void gemm_qkv(
    const unsigned short* __restrict__ W, const unsigned short* __restrict__ HN,
    const float* __restrict__ qb, const float* __restrict__ kb,
    const float* __restrict__ vb, unsigned short* __restrict__ Q2,
    unsigned short* __restrict__ K2, unsigned short* __restrict__ V2,
    float scale) {
  int flat = blockIdx.x + 12 * (blockIdx.y + 8 * blockIdx.z);  // 1536 = 8*192
  int nf = (flat & 7) * 192 + (flat >> 3);
  int bxi = nf % 12, rem = nf / 12;
  int byi = rem & 7, bz = rem >> 3;
  const unsigned short* Ab = W + (long)bxi * 128 * 512;
  const unsigned short* Bb = HN + (long)bz * N_ * C_ + (long)byi * 128 * 512;
  __shared__ char lds[32768];
  char* As = lds;
  char* Bs = lds + 16384;
  int tid = threadIdx.x;
  int lane = tid & 63, wave = tid >> 6;
  int wr = wave >> 1, wc = wave & 1;
  int lrow = lane & 15, kgrp = lane >> 4;
  f32x4_t acc[4][4];
#pragma unroll
  for (int i = 0; i < 4; ++i)
#pragma unroll
    for (int j = 0; j < 4; ++j) acc[i][j] = (f32x4_t){0.f, 0.f, 0.f, 0.f};

  int perm = (((lane & 7) ^ (lane >> 3)) << 3);
  const unsigned short* Asrc = Ab + (long)(wave * 32 + (lane >> 3)) * 512 + perm;
  const unsigned short* Bsrc = Bb + (long)(wave * 32 + (lane >> 3)) * 512 + perm;
  char* Adst = As + wave * 32 * 128;
  char* Bdst = Bs + wave * 32 * 128;

  for (int kt = 0; kt < 8; ++kt) {
    __syncthreads();
#pragma unroll
    for (int i = 0; i < 4; ++i) {
      gload_lds16(Asrc + (long)i * 8 * 512 + kt * 64, Adst + i * 1024);
      gload_lds16(Bsrc + (long)i * 8 * 512 + kt * 64, Bdst + i * 1024);
    }
    __syncthreads();
#pragma unroll
    for (int ks = 0; ks < 2; ++ks) {
      bf16x8_t af[4], bfv[4];
#pragma unroll
      for (int mi = 0; mi < 4; ++mi) {
        int r = wr * 64 + mi * 16 + lrow;
        int o = r * 128 + ks * 64 + kgrp * 16;
        o ^= (r & 7) << 4;
        af[mi] = *(bf16x8_t*)(As + o);
      }
#pragma unroll
      for (int ni = 0; ni < 4; ++ni) {
        int r = wc * 64 + ni * 16 + lrow;
        int o = r * 128 + ks * 64 + kgrp * 16;
        o ^= (r & 7) << 4;
        bfv[ni] = *(bf16x8_t*)(Bs + o);
      }
#pragma unroll
      for (int mi = 0; mi < 4; ++mi)
#pragma unroll
        for (int ni = 0; ni < 4; ++ni)
          acc[mi][ni] = mfma16(af[mi], bfv[ni], acc[mi][ni]);
    }
  }

  int slab = bxi >> 2;
  const float* bias = slab == 0 ? qb : (slab == 1 ? kb : vb);
  float scl = slab == 0 ? scale : 1.f;
  int rowloc = (bxi & 3) * 128 + wr * 64;  // c within slab
  int colbase = byi * 128 + wc * 64;       // n
  unsigned short* ob =
      (slab == 0 ? Q2 : (slab == 1 ? K2 : V2)) + ((long)bz << 19);
#pragma unroll
  for (int mi = 0; mi < 4; ++mi) {
#pragma unroll
    for (int ni = 0; ni < 4; ++ni) {
      int row0 = rowloc + mi * 16 + kgrp * 4;
      int col = colbase + ni * 16 + lrow;
      unsigned short us[4];
#pragma unroll
      for (int rg = 0; rg < 4; ++rg)
        us[rg] = f2bf((acc[mi][ni][rg] + bias[row0 + rg]) * scl);
      if (slab < 2) {
        long off = ((long)(col >> 4) << 13) + ((long)(row0 >> 3) << 7) +
                   ((col & 15) << 3) + (row0 & 7);
        *(ushort4*)(ob + off) = make_ushort4(us[0], us[1], us[2], us[3]);
      } else {
        long base16 = ((long)(row0 >> 4) << 14) + ((long)(col >> 3) << 7) +
                      (col & 7) + (row0 & 15) * 8;
#pragma unroll
        for (int rg = 0; rg < 4; ++rg) ob[base16 + rg * 8] = us[rg];
      }
    }
  }
}

// ---------------------------------------------------------------- fused attn+PV+proj
// 256 blocks x 512 threads; b = f&15 pins batch to XCD b%8.
// Phases: (1) QK^T (transposed, Q LDS-staged, K frag 1KB loads) (2) exp2 +
// P stage (no max-sub) (3) PV from V2 frags (4) NEW: normalized AO staged
// frag-blocked into dead P2 LDS, then proj: out = Wp*AO^T + pbias + x,
// Wp A-frags direct from L2 (frag-blocked Wpf, batched 4/ks). Eliminates the
// AO HBM round-trip and the separate proj dispatch; proj's MFMA + HBM stream
// ride in attn's idle issue slots (HBM was 13%, MFMA-busy ~5 of 41 us).
__global__ __launch_bounds__(512, 1) void attn_fused_k(
    const unsigned short* __restrict__ q2, const unsigned short* __restrict__ k2,
    const unsigned short* __restrict__ v2, const unsigned short* __restrict__ wpf,
    const float* __restrict__ pbias, const float* __restrict__ x,
    float* __restrict__ out) {
  int f = blockIdx.x;
  int b = f & 15, ib = f >> 4;  // rows ib*64..+64
  int tid = threadIdx.x, lane = tid & 63, wave = tid >> 6;  // 8 waves
  int lrow = lane & 15, kgrp = lane >> 4;
  __shared__ unsigned short P2[65536];  // 128KB; reused: Q stage -> P -> AO
  __shared__ float red1[8][64];
  __shared__ float invr[64];
  // ---- stage Q: 64KB contiguous -> P2[0..32768) linear ----
  {
    const unsigned short* qsrc =
        q2 + ((long)b << 19) + ((long)(ib * 4) << 13) + wave * 4096 + lane * 8;
    char* qdst = (char*)P2 + wave * 8192;
#pragma unroll
    for (int i = 0; i < 8; ++i) gload_lds16(qsrc + i * 512, qdst + i * 1024);
  }
  asm volatile("s_waitcnt vmcnt(0)" ::: "memory");
  __syncthreads();
  f32x4_t acc[4][8];
#pragma unroll
  for (int h = 0; h < 4; ++h)
#pragma unroll
    for (int t = 0; t < 8; ++t) acc[h][t] = (f32x4_t){0.f, 0.f, 0.f, 0.f};
  const unsigned short* kb =
      k2 + ((long)b << 19) + ((long)(wave * 8) << 13) + lane * 8;
  for (int ks = 0; ks < 16; ++ks) {  // K = 512
    bf16x8_t kf[8];
#pragma unroll
    for (int t = 0; t < 8; ++t)
      kf[t] = *(const bf16x8_t*)(kb + t * 8192 + ks * 512);
    bf16x8_t qa[4];
#pragma unroll
    for (int h = 0; h < 4; ++h)
      qa[h] = *(const bf16x8_t*)&P2[h * 8192 + ks * 512 + lane * 8];
    __builtin_amdgcn_s_setprio(1);
#pragma unroll
    for (int h = 0; h < 4; ++h)
#pragma unroll
      for (int t = 0; t < 8; ++t) acc[h][t] = mfma16(kf[t], qa[h], acc[h][t]);
    __builtin_amdgcn_s_setprio(0);
  }
  // acc[h][t][rg] = score[j = wave*128 + t*16 + kgrp*4 + rg][i = h*16 + lrow]
  __syncthreads();  // all waves past K-loop: Q dead, P2 region writable
  // ---- exp2 (no max subtraction) + vectorized P stage + row sums ----
  float sm[4] = {0.f, 0.f, 0.f, 0.f};
#pragma unroll
  for (int h = 0; h < 4; ++h) {
#pragma unroll
    for (int t = 0; t < 8; ++t) {
      int jb = wave * 16 + t * 2 + (kgrp >> 1);
      int off = h * 16384 + jb * 128 + (((lrow ^ (jb & 7)) << 3) | ((kgrp & 1) << 2));
      unsigned short us[4];
#pragma unroll
      for (int rg = 0; rg < 4; ++rg) {
        float p = exp2f(acc[h][t][rg]);  // scores already in log2 domain
        sm[h] += p;
        us[rg] = f2bf(p);
      }
      *(ushort4*)&P2[off] = make_ushort4(us[0], us[1], us[2], us[3]);
    }
  }
#pragma unroll
  for (int m = 16; m < 64; m <<= 1)
#pragma unroll
    for (int h = 0; h < 4; ++h) sm[h] += __shfl_xor(sm[h], m);
  if (kgrp == 0) {
#pragma unroll
    for (int h = 0; h < 4; ++h) red1[wave][h * 16 + lrow] = sm[h];
  }
  __syncthreads();  // P2 + red1 complete
  if (tid < 64) {
    float s = red1[0][tid];
#pragma unroll
    for (int w = 1; w < 8; ++w) s += red1[w][tid];
    invr[tid] = 1.f / s;
  }
  __syncthreads();
  // ---- PV: wave owns channels [wave*64, +64), 2-deep V prefetch ----
  f32x4_t o[4][4];
#pragma unroll
  for (int h = 0; h < 4; ++h)
#pragma unroll
    for (int cf = 0; cf < 4; ++cf) o[h][cf] = (f32x4_t){0.f, 0.f, 0.f, 0.f};
  const char* vb2 =
      (const char*)(v2 + ((long)b << 19) + ((long)(wave * 4) << 14)) + lane * 16;
  bf16x8_t vc[4];
#pragma unroll
  for (int cf = 0; cf < 4; ++cf) vc[cf] = *(const bf16x8_t*)(vb2 + cf * 32768);
#pragma unroll
  for (int js = 0; js < 32; ++js) {
    bf16x8_t vn[4];
    if (js < 31) {
#pragma unroll
      for (int cf = 0; cf < 4; ++cf)
        vn[cf] = *(const bf16x8_t*)(vb2 + cf * 32768 + (js + 1) * 1024);
    }
    int jb = js * 4 + kgrp;
    int pox = ((lrow ^ (jb & 7)) << 3) + jb * 128;
    bf16x8_t pa[4];
#pragma unroll
    for (int h = 0; h < 4; ++h)
      pa[h] = *(const bf16x8_t*)&P2[h * 16384 + pox];
    __builtin_amdgcn_s_setprio(1);
#pragma unroll
    for (int h = 0; h < 4; ++h)
#pragma unroll
      for (int cf = 0; cf < 4; ++cf)
        o[h][cf] = mfma16(pa[h], vc[cf], o[h][cf]);
    __builtin_amdgcn_s_setprio(0);
    if (js < 31) {
#pragma unroll
      for (int cf = 0; cf < 4; ++cf) vc[cf] = vn[cf];
    }
  }
  __syncthreads();  // ALL waves done reading P (PV complete); P2 reusable
  // ---- stage normalized AO (bf16) frag-blocked [i/16][c/8][i%16][c%8] ----
  // off = h*8192 + (c>>3)*128 + (i&15)*8 + (c&7); i = h*16+kgrp*4+rg,
  // c = wave*64+cf*16+lrow.
#pragma unroll
  for (int h = 0; h < 4; ++h) {
#pragma unroll
    for (int cf = 0; cf < 4; ++cf) {
      int c = wave * 64 + cf * 16 + lrow;
      int cb = (c >> 3) * 128 + (c & 7);
#pragma unroll
      for (int rg = 0; rg < 4; ++rg) {
        float inv = invr[h * 16 + kgrp * 4 + rg];
        P2[h * 8192 + cb + ((kgrp * 4 + rg) << 3)] =
            f2bf(o[h][cf][rg] * inv);
      }
    }
  }
  __syncthreads();  // AO stage complete
  // ---- proj: wave owns c_out [wave*64, +64); A = Wpf (L2), B = AO (LDS) ----
  f32x4_t pacc[4][4];
#pragma unroll
  for (int mi = 0; mi < 4; ++mi)
#pragma unroll
    for (int ni = 0; ni < 4; ++ni) pacc[mi][ni] = (f32x4_t){0.f, 0.f, 0.f, 0.f};
  const unsigned short* wpb = wpf + (long)wave * 32768 + lane * 8;
  for (int ks = 0; ks < 16; ++ks) {  // K = c_in = 512
    bf16x8_t af[4], bfv[4];
#pragma unroll
    for (int mi = 0; mi < 4; ++mi)
      af[mi] = *(const bf16x8_t*)(wpb + mi * 8192 + ks * 512);
#pragma unroll
    for (int ni = 0; ni < 4; ++ni)
      bfv[ni] = *(const bf16x8_t*)&P2[ni * 8192 + ks * 512 + lane * 8];
    __builtin_amdgcn_s_setprio(1);
#pragma unroll
    for (int mi = 0; mi < 4; ++mi)
#pragma unroll
      for (int ni = 0; ni < 4; ++ni)
        pacc[mi][ni] = mfma16(af[mi], bfv[ni], pacc[mi][ni]);
    __builtin_amdgcn_s_setprio(0);
  }
  // epilogue: out[b][c][ib*64 + n] = pacc + pbias[c] + x[b][c][ib*64 + n]
  float* ob = out + (long)b * C_ * N_ + ib * 64;
  const float* xb = x + (long)b * C_ * N_ + ib * 64;
#pragma unroll
  for (int mi = 0; mi < 4; ++mi) {
#pragma unroll
    for (int ni = 0; ni < 4; ++ni) {
      int n = ni * 16 + lrow;
#pragma unroll
      for (int rg = 0; rg < 4; ++rg) {
        int c = wave * 64 + mi * 16 + kgrp * 4 + rg;
        ob[(long)c * N_ + n] = pacc[mi][ni][rg] + pbias[c] + xb[(long)c * N_ + n];
      }
    }
  }
}

// ---------------------------------------------------------------- launch
extern "C" void kernel_launch(void* const* d_in, const int* in_sizes, int n_in,
                              void* d_out, int out_size, void* d_ws,
                              size_t ws_size, hipStream_t stream) {
  (void)in_sizes; (void)n_in; (void)out_size; (void)ws_size;
  const float* x = (const float*)d_in[0];
  const float* nw = (const float*)d_in[1];
  const float* nb = (const float*)d_in[2];
  const float* qw = (const float*)d_in[3];
  const float* qbias = (const float*)d_in[4];
  const float* kw = (const float*)d_in[5];
  const float* kbias = (const float*)d_in[6];
  const float* vw = (const float*)d_in[7];
  const float* vbias = (const float*)d_in[8];
  const float* pw = (const float*)d_in[9];
  const float* pbias = (const float*)d_in[10];
  float* out = (float*)d_out;

  char* ws = (char*)d_ws;
  unsigned short* WQKV = (unsigned short*)(ws + 0);        // 1.5MB stacked
  unsigned short* Wpf = (unsigned short*)(ws + 1572864);   // 0.5MB frag-blocked
  unsigned short* HN = (unsigned short*)(ws + 2097152);    // 16MB (b,n,c)
  unsigned short* Q2 = (unsigned short*)(ws + 18874368);   // 16MB frag [n/16][c/8]
  unsigned short* K2 = (unsigned short*)(ws + 35651584);   // 16MB frag [n/16][c/8]
  unsigned short* V2 = (unsigned short*)(ws + 52428800);   // 16MB frag [c/16][n/8]

  castw_k<<<128, 256, 0, stream>>>(qw, kw, vw, pw, WQKV, Wpf);
  gn_fused_k<<<256, 512, 0, stream>>>(x, nw, nb, HN);

  // 512^-0.5 * log2(e): scores land in the exp2 domain for native exp2f
  const float scale = 0.06375871512f;
  // q,k,v in one dispatch
  gemm_qkv<<<dim3(12, 8, B_), 256, 0, stream>>>(WQKV, HN, qbias, kbias, vbias,
                                                Q2, K2, V2, scale);
  // fused QK^T + softmax + PV + proj + residual -> out (fp32)
  attn_fused_k<<<256, 512, 0, stream>>>(Q2, K2, V2, Wpf, pbias, x, out);
}

// Round 21
// 100.326 us; speedup vs baseline: 1.2774x; 1.0178x over previous
//
#include <hip/hip_runtime.h>

#define B_ 16
#define C_ 512
#define N_ 1024

typedef __attribute__((ext_vector_type(8))) short bf16x8_t;
typedef __attribute__((ext_vector_type(4))) float f32x4_t;

__device__ __forceinline__ unsigned short f2bf(float f) {
  unsigned int u = __float_as_uint(f);
  u += 0x7fffu + ((u >> 16) & 1u);
  return (unsigned short)(u >> 16);
}

__device__ __forceinline__ f32x4_t mfma16(bf16x8_t a, bf16x8_t b, f32x4_t c) {
  return __builtin_amdgcn_mfma_f32_16x16x32_bf16(a, b, c, 0, 0, 0);
}

// async global->LDS, 16B per lane; dest is wave-uniform base (lane*16 added by HW)
__device__ __forceinline__ void gload_lds16(const void* g, void* l) {
  __builtin_amdgcn_global_load_lds(
      (const __attribute__((address_space(1))) unsigned int*)g,
      (__attribute__((address_space(3))) unsigned int*)l, 16, 0, 0);
}

// ---------------------------------------------------------------- GN + castw
// Blocks 0..255: fused GroupNorm (reads the 32ch x 1024 fp32 slab once via
// LDS, full-64B-line transposed bf16 stores). Blocks 256..319: weight cast —
// Wq|Wk|Wv -> linear stacked; Wp -> frag-blocked Wpf[c_out/16][c_in/8][...]
// for the fused attn+proj kernel. Merged so the cast rides under GN's HBM
// streaming instead of serializing ~2us ahead of it.
__global__ __launch_bounds__(512, 1) void gn_castw_k(
    const float* __restrict__ x, const float* __restrict__ gw,
    const float* __restrict__ gb, unsigned short* __restrict__ hn,
    const float* __restrict__ qw, const float* __restrict__ kw,
    const float* __restrict__ vw, const float* __restrict__ pw,
    unsigned short* __restrict__ Wqkv, unsigned short* __restrict__ Wpf) {
  __shared__ float xs[32768];      // [c][n ^ (((c>>3)&3)<<4)] = 128KB
  __shared__ float red[2][2][8];   // [sum/sq][group][wave]
  int blk = blockIdx.x;
  if (blk >= 256) {  // ---- weight-cast path ----
    int idx = (blk - 256) * 512 + threadIdx.x;  // 0..32767
    int m = idx >> 6;         // row 0..511
    int k0 = (idx & 63) * 8;  // k octet base
    long lin = (long)m * 512 + k0;
#pragma unroll
    for (int s = 0; s < 3; ++s) {
      const float* src = s == 0 ? qw : (s == 1 ? kw : vw);
      float4 a = *(const float4*)(src + lin);
      float4 b = *(const float4*)(src + lin + 4);
      unsigned short us[8] = {f2bf(a.x), f2bf(a.y), f2bf(a.z), f2bf(a.w),
                              f2bf(b.x), f2bf(b.y), f2bf(b.z), f2bf(b.w)};
      *(uint4*)(Wqkv + s * 262144 + lin) = *(uint4*)us;
    }
    float4 d = *(const float4*)(pw + lin);
    float4 d2 = *(const float4*)(pw + lin + 4);
    unsigned short up[8] = {f2bf(d.x),  f2bf(d.y),  f2bf(d.z),  f2bf(d.w),
                            f2bf(d2.x), f2bf(d2.y), f2bf(d2.z), f2bf(d2.w)};
    long fp = ((long)(m >> 4) << 13) + ((k0 >> 3) << 7) + ((m & 15) << 3);
    *(uint4*)(Wpf + fp) = *(uint4*)up;
    return;
  }
  // ---- GroupNorm path ----
  int b = blk >> 4, gp = blk & 15;
  int t = threadIdx.x, lane = t & 63, wave = t >> 6;
  const float* xg = x + ((long)b * C_ + gp * 32) * N_;  // 128KB contiguous
  float s0 = 0.f, s20 = 0.f, s1 = 0.f, s21 = 0.f;
#pragma unroll
  for (int i = 0; i < 16; ++i) {
    int f4 = t + 512 * i;
    float4 v = ((const float4*)xg)[f4];
    float sum = v.x + v.y + v.z + v.w;
    float sq = v.x * v.x + v.y * v.y + v.z * v.z + v.w * v.w;
    if (i < 8) { s0 += sum; s20 += sq; } else { s1 += sum; s21 += sq; }
    int fi = f4 << 2;
    int c = fi >> 10, n = fi & 1023;
    int nx = n ^ (((c >> 3) & 3) << 4);
    *(float4*)&xs[(c << 10) + nx] = v;
  }
#pragma unroll
  for (int m = 1; m < 64; m <<= 1) {
    s0 += __shfl_xor(s0, m); s20 += __shfl_xor(s20, m);
    s1 += __shfl_xor(s1, m); s21 += __shfl_xor(s21, m);
  }
  if (lane == 0) {
    red[0][0][wave] = s0; red[1][0][wave] = s20;
    red[0][1][wave] = s1; red[1][1][wave] = s21;
  }
  __syncthreads();
  float m0 = 0.f, v0 = 0.f, m1 = 0.f, v1 = 0.f;
#pragma unroll
  for (int w = 0; w < 8; ++w) {
    m0 += red[0][0][w]; v0 += red[1][0][w];
    m1 += red[0][1][w]; v1 += red[1][1][w];
  }
  m0 *= (1.f / 16384.f); m1 *= (1.f / 16384.f);
  float rv0 = rsqrtf(v0 * (1.f / 16384.f) - m0 * m0 + 1e-5f);
  float rv1 = rsqrtf(v1 * (1.f / 16384.f) - m1 * m1 + 1e-5f);
  int q = t & 3;
  float mean = (q >> 1) ? m1 : m0, rv = (q >> 1) ? rv1 : rv0;
  float ga[8], be[8];
#pragma unroll
  for (int jj = 0; jj < 8; ++jj) {
    int gc = gp * 32 + q * 8 + jj;
    ga[jj] = gw[gc] * rv;
    be[jj] = gb[gc] - mean * ga[jj];
  }
  unsigned short* ob = hn + (long)b * N_ * C_ + gp * 32 + q * 8;
  int n0 = t >> 2;  // 0..127
  for (int it = 0; it < 8; ++it) {
    int n = n0 + (it << 7);
    int nsw = n ^ (q << 4);
    unsigned short us[8];
#pragma unroll
    for (int jj = 0; jj < 8; ++jj) {
      int c = q * 8 + jj;
      us[jj] = f2bf(xs[(c << 10) + nsw] * ga[jj] + be[jj]);
    }
    *(uint4*)(ob + (long)n * C_) = *(uint4*)us;
  }
}

// ---------------------------------------------------------------- QKV GEMM
// Champion form: merged single dispatch, 32KB single-buffered LDS, 2
// barriers/kt. Epilogue per 512-row slab: 0 -> Q2 (*scale), 1 -> K2
// frag-blocked ushort4; 2 -> V2 [c/16][n/8][c%16][n%8] scalar stores.
__global__ __launch_bounds__(256) void gemm_qkv(
    const unsigned short* __restrict__ W, const unsigned short* __restrict__ HN,
    const float* __restrict__ qb, const float* __restrict__ kb,
    const float* __restrict__ vb, unsigned short* __restrict__ Q2,
    unsigned short* __restrict__ K2, unsigned short* __restrict__ V2,
    float scale) {
  int flat = blockIdx.x + 12 * (blockIdx.y + 8 * blockIdx.z);  // 1536 = 8*192
  int nf = (flat & 7) * 192 + (flat >> 3);
  int bxi = nf % 12, rem = nf / 12;
  int byi = rem & 7, bz = rem >> 3;
  const unsigned short* Ab = W + (long)bxi * 128 * 512;
  const unsigned short* Bb = HN + (long)bz * N_ * C_ + (long)byi * 128 * 512;
  __shared__ char lds[32768];
  char* As = lds;
  char* Bs = lds + 16384;
  int tid = threadIdx.x;
  int lane = tid & 63, wave = tid >> 6;
  int wr = wave >> 1, wc = wave & 1;
  int lrow = lane & 15, kgrp = lane >> 4;
  f32x4_t acc[4][4];
#pragma unroll
  for (int i = 0; i < 4; ++i)
#pragma unroll
    for (int j = 0; j < 4; ++j) acc[i][j] = (f32x4_t){0.f, 0.f, 0.f, 0.f};

  int perm = (((lane & 7) ^ (lane >> 3)) << 3);
  const unsigned short* Asrc = Ab + (long)(wave * 32 + (lane >> 3)) * 512 + perm;
  const unsigned short* Bsrc = Bb + (long)(wave * 32 + (lane >> 3)) * 512 + perm;
  char* Adst = As + wave * 32 * 128;
  char* Bdst = Bs + wave * 32 * 128;

  for (int kt = 0; kt < 8; ++kt) {
    __syncthreads();
#pragma unroll
    for (int i = 0; i < 4; ++i) {
      gload_lds16(Asrc + (long)i * 8 * 512 + kt * 64, Adst + i * 1024);
      gload_lds16(Bsrc + (long)i * 8 * 512 + kt * 64, Bdst + i * 1024);
    }
    __syncthreads();
#pragma unroll
    for (int ks = 0; ks < 2; ++ks) {
      bf16x8_t af[4], bfv[4];
#pragma unroll
      for (int mi = 0; mi < 4; ++mi) {
        int r = wr * 64 + mi * 16 + lrow;
        int o = r * 128 + ks * 64 + kgrp * 16;
        o ^= (r & 7) << 4;
        af[mi] = *(bf16x8_t*)(As + o);
      }
#pragma unroll
      for (int ni = 0; ni < 4; ++ni) {
        int r = wc * 64 + ni * 16 + lrow;
        int o = r * 128 + ks * 64 + kgrp * 16;
        o ^= (r & 7) << 4;
        bfv[ni] = *(bf16x8_t*)(Bs + o);
      }
#pragma unroll
      for (int mi = 0; mi < 4; ++mi)
#pragma unroll
        for (int ni = 0; ni < 4; ++ni)
          acc[mi][ni] = mfma16(af[mi], bfv[ni], acc[mi][ni]);
    }
  }

  int slab = bxi >> 2;
  const float* bias = slab == 0 ? qb : (slab == 1 ? kb : vb);
  float scl = slab == 0 ? scale : 1.f;
  int rowloc = (bxi & 3) * 128 + wr * 64;  // c within slab
  int colbase = byi * 128 + wc * 64;       // n
  unsigned short* ob =
      (slab == 0 ? Q2 : (slab == 1 ? K2 : V2)) + ((long)bz << 19);
#pragma unroll
  for (int mi = 0; mi < 4; ++mi) {
#pragma unroll
    for (int ni = 0; ni < 4; ++ni) {
      int row0 = rowloc + mi * 16 + kgrp * 4;
      int col = colbase + ni * 16 + lrow;
      unsigned short us[4];
#pragma unroll
      for (int rg = 0; rg < 4; ++rg)
        us[rg] = f2bf((acc[mi][ni][rg] + bias[row0 + rg]) * scl);
      if (slab < 2) {
        long off = ((long)(col >> 4) << 13) + ((long)(row0 >> 3) << 7) +
                   ((col & 15) << 3) + (row0 & 7);
        *(ushort4*)(ob + off) = make_ushort4(us[0], us[1], us[2], us[3]);
      } else {
        long base16 = ((long)(row0 >> 4) << 14) + ((long)(col >> 3) << 7) +
                      (col & 7) + (row0 & 15) * 8;
#pragma unroll
        for (int rg = 0; rg < 4; ++rg) ob[base16 + rg * 8] = us[rg];
      }
    }
  }
}

// ---------------------------------------------------------------- fused attn+PV+proj
// 256 blocks x 512 threads; b = f&15 pins batch to XCD b%8.
// Phases: (1) QK^T (transposed, Q LDS-staged, K frag 1KB loads) (2) exp2 +
// P stage (no max-sub) (3) PV computed TRANSPOSED (mfma(vc,pa): D rows = c,
// so rg varies c) -> AO stage is 32 ushort4 LDS stores at ~2-way (free) bank
// aliasing instead of 128 scalar stores, inv lookup uniform per (h,lane).
// (4) proj: out = Wp*AO^T + pbias + x, Wp A-frags direct from L2 (Wpf).
__global__ __launch_bounds__(512, 1) void attn_fused_k(
    const unsigned short* __restrict__ q2, const unsigned short* __restrict__ k2,
    const unsigned short* __restrict__ v2, const unsigned short* __restrict__ wpf,
    const float* __restrict__ pbias, const float* __restrict__ x,
    float* __restrict__ out) {
  int f = blockIdx.x;
  int b = f & 15, ib = f >> 4;  // rows ib*64..+64
  int tid = threadIdx.x, lane = tid & 63, wave = tid >> 6;  // 8 waves
  int lrow = lane & 15, kgrp = lane >> 4;
  __shared__ unsigned short P2[65536];  // 128KB; reused: Q stage -> P -> AO
  __shared__ float red1[8][64];
  __shared__ float invr[64];
  // ---- stage Q: 64KB contiguous -> P2[0..32768) linear ----
  {
    const unsigned short* qsrc =
        q2 + ((long)b << 19) + ((long)(ib * 4) << 13) + wave * 4096 + lane * 8;
    char* qdst = (char*)P2 + wave * 8192;
#pragma unroll
    for (int i = 0; i < 8; ++i) gload_lds16(qsrc + i * 512, qdst + i * 1024);
  }
  asm volatile("s_waitcnt vmcnt(0)" ::: "memory");
  __syncthreads();
  f32x4_t acc[4][8];
#pragma unroll
  for (int h = 0; h < 4; ++h)
#pragma unroll
    for (int t = 0; t < 8; ++t) acc[h][t] = (f32x4_t){0.f, 0.f, 0.f, 0.f};
  const unsigned short* kb =
      k2 + ((long)b << 19) + ((long)(wave * 8) << 13) + lane * 8;
  for (int ks = 0; ks < 16; ++ks) {  // K = 512
    bf16x8_t kf[8];
#pragma unroll
    for (int t = 0; t < 8; ++t)
      kf[t] = *(const bf16x8_t*)(kb + t * 8192 + ks * 512);
    bf16x8_t qa[4];
#pragma unroll
    for (int h = 0; h < 4; ++h)
      qa[h] = *(const bf16x8_t*)&P2[h * 8192 + ks * 512 + lane * 8];
    __builtin_amdgcn_s_setprio(1);
#pragma unroll
    for (int h = 0; h < 4; ++h)
#pragma unroll
      for (int t = 0; t < 8; ++t) acc[h][t] = mfma16(kf[t], qa[h], acc[h][t]);
    __builtin_amdgcn_s_setprio(0);
  }
  // acc[h][t][rg] = score[j = wave*128 + t*16 + kgrp*4 + rg][i = h*16 + lrow]
  __syncthreads();  // all waves past K-loop: Q dead, P2 region writable
  // ---- exp2 (no max subtraction) + vectorized P stage + row sums ----
  float sm[4] = {0.f, 0.f, 0.f, 0.f};
#pragma unroll
  for (int h = 0; h < 4; ++h) {
#pragma unroll
    for (int t = 0; t < 8; ++t) {
      int jb = wave * 16 + t * 2 + (kgrp >> 1);
      int off = h * 16384 + jb * 128 + (((lrow ^ (jb & 7)) << 3) | ((kgrp & 1) << 2));
      unsigned short us[4];
#pragma unroll
      for (int rg = 0; rg < 4; ++rg) {
        float p = exp2f(acc[h][t][rg]);  // scores already in log2 domain
        sm[h] += p;
        us[rg] = f2bf(p);
      }
      *(ushort4*)&P2[off] = make_ushort4(us[0], us[1], us[2], us[3]);
    }
  }
#pragma unroll
  for (int m = 16; m < 64; m <<= 1)
#pragma unroll
    for (int h = 0; h < 4; ++h) sm[h] += __shfl_xor(sm[h], m);
  if (kgrp == 0) {
#pragma unroll
    for (int h = 0; h < 4; ++h) red1[wave][h * 16 + lrow] = sm[h];
  }
  __syncthreads();  // P2 + red1 complete
  if (tid < 64) {
    float s = red1[0][tid];
#pragma unroll
    for (int w = 1; w < 8; ++w) s += red1[w][tid];
    invr[tid] = 1.f / s;
  }
  __syncthreads();
  // ---- PV (transposed): o[cf][h] rows = c, cols = i; 2-deep V prefetch ----
  f32x4_t o[4][4];
#pragma unroll
  for (int cf = 0; cf < 4; ++cf)
#pragma unroll
    for (int h = 0; h < 4; ++h) o[cf][h] = (f32x4_t){0.f, 0.f, 0.f, 0.f};
  const char* vb2 =
      (const char*)(v2 + ((long)b << 19) + ((long)(wave * 4) << 14)) + lane * 16;
  bf16x8_t vc[4];
#pragma unroll
  for (int cf = 0; cf < 4; ++cf) vc[cf] = *(const bf16x8_t*)(vb2 + cf * 32768);
#pragma unroll
  for (int js = 0; js < 32; ++js) {
    bf16x8_t vn[4];
    if (js < 31) {
#pragma unroll
      for (int cf = 0; cf < 4; ++cf)
        vn[cf] = *(const bf16x8_t*)(vb2 + cf * 32768 + (js + 1) * 1024);
    }
    int jb = js * 4 + kgrp;
    int pox = ((lrow ^ (jb & 7)) << 3) + jb * 128;
    bf16x8_t pa[4];
#pragma unroll
    for (int h = 0; h < 4; ++h)
      pa[h] = *(const bf16x8_t*)&P2[h * 16384 + pox];
    __builtin_amdgcn_s_setprio(1);
#pragma unroll
    for (int cf = 0; cf < 4; ++cf)
#pragma unroll
      for (int h = 0; h < 4; ++h)
        o[cf][h] = mfma16(vc[cf], pa[h], o[cf][h]);  // transposed PV
    __builtin_amdgcn_s_setprio(0);
    if (js < 31) {
#pragma unroll
      for (int cf = 0; cf < 4; ++cf) vc[cf] = vn[cf];
    }
  }
  __syncthreads();  // ALL waves done reading P (PV complete); P2 reusable
  // ---- stage normalized AO (bf16) frag-blocked [i/16][c/8][i%16][c%8] ----
  // o[cf][h][rg]: c = wave*64 + cf*16 + kgrp*4 + rg, i = h*16 + lrow.
  // elem off = h*8192 + (c>>3)*128 + lrow*8 + (kgrp&1)*4 -> ushort4 stores.
  float invv[4];
#pragma unroll
  for (int h = 0; h < 4; ++h) invv[h] = invr[h * 16 + lrow];
#pragma unroll
  for (int cf = 0; cf < 4; ++cf) {
    int cb = wave * 8 + cf * 2 + (kgrp >> 1);  // c>>3
#pragma unroll
    for (int h = 0; h < 4; ++h) {
      unsigned short us[4];
#pragma unroll
      for (int rg = 0; rg < 4; ++rg) us[rg] = f2bf(o[cf][h][rg] * invv[h]);
      *(ushort4*)&P2[h * 8192 + cb * 128 + lrow * 8 + ((kgrp & 1) << 2)] =
          make_ushort4(us[0], us[1], us[2], us[3]);
    }
  }
  __syncthreads();  // AO stage complete
  // ---- proj: wave owns c_out [wave*64, +64); A = Wpf (L2), B = AO (LDS) ----
  f32x4_t pacc[4][4];
#pragma unroll
  for (int mi = 0; mi < 4; ++mi)
#pragma unroll
    for (int ni = 0; ni < 4; ++ni) pacc[mi][ni] = (f32x4_t){0.f, 0.f, 0.f, 0.f};
  const unsigned short* wpb = wpf + (long)wave * 32768 + lane * 8;
  for (int ks = 0; ks < 16; ++ks) {  // K = c_in = 512
    bf16x8_t af[4], bfv[4];
#pragma unroll
    for (int mi = 0; mi < 4; ++mi)
      af[mi] = *(const bf16x8_t*)(wpb + mi * 8192 + ks * 512);
#pragma unroll
    for (int ni = 0; ni < 4; ++ni)
      bfv[ni] = *(const bf16x8_t*)&P2[ni * 8192 + ks * 512 + lane * 8];
    __builtin_amdgcn_s_setprio(1);
#pragma unroll
    for (int mi = 0; mi < 4; ++mi)
#pragma unroll
      for (int ni = 0; ni < 4; ++ni)
        pacc[mi][ni] = mfma16(af[mi], bfv[ni], pacc[mi][ni]);
    __builtin_amdgcn_s_setprio(0);
  }
  // epilogue: out[b][c][ib*64 + n] = pacc + pbias[c] + x[b][c][ib*64 + n]
  float* ob = out + (long)b * C_ * N_ + ib * 64;
  const float* xb = x + (long)b * C_ * N_ + ib * 64;
#pragma unroll
  for (int mi = 0; mi < 4; ++mi) {
#pragma unroll
    for (int ni = 0; ni < 4; ++ni) {
      int n = ni * 16 + lrow;
#pragma unroll
      for (int rg = 0; rg < 4; ++rg) {
        int c = wave * 64 + mi * 16 + kgrp * 4 + rg;
        ob[(long)c * N_ + n] = pacc[mi][ni][rg] + pbias[c] + xb[(long)c * N_ + n];
      }
    }
  }
}

// ---------------------------------------------------------------- launch
extern "C" void kernel_launch(void* const* d_in, const int* in_sizes, int n_in,
                              void* d_out, int out_size, void* d_ws,
                              size_t ws_size, hipStream_t stream) {
  (void)in_sizes; (void)n_in; (void)out_size; (void)ws_size;
  const float* x = (const float*)d_in[0];
  const float* nw = (const float*)d_in[1];
  const float* nb = (const float*)d_in[2];
  const float* qw = (const float*)d_in[3];
  const float* qbias = (const float*)d_in[4];
  const float* kw = (const float*)d_in[5];
  const float* kbias = (const float*)d_in[6];
  const float* vw = (const float*)d_in[7];
  const float* vbias = (const float*)d_in[8];
  const float* pw = (const float*)d_in[9];
  const float* pbias = (const float*)d_in[10];
  float* out = (float*)d_out;

  char* ws = (char*)d_ws;
  unsigned short* WQKV = (unsigned short*)(ws + 0);        // 1.5MB stacked
  unsigned short* Wpf = (unsigned short*)(ws + 1572864);   // 0.5MB frag-blocked
  unsigned short* HN = (unsigned short*)(ws + 2097152);    // 16MB (b,n,c)
  unsigned short* Q2 = (unsigned short*)(ws + 18874368);   // 16MB frag [n/16][c/8]
  unsigned short* K2 = (unsigned short*)(ws + 35651584);   // 16MB frag [n/16][c/8]
  unsigned short* V2 = (unsigned short*)(ws + 52428800);   // 16MB frag [c/16][n/8]

  // GN (blocks 0..255) + weight cast (blocks 256..319) in one dispatch
  gn_castw_k<<<320, 512, 0, stream>>>(x, nw, nb, HN, qw, kw, vw, pw, WQKV, Wpf);

  // 512^-0.5 * log2(e): scores land in the exp2 domain for native exp2f
  const float scale = 0.06375871512f;
  // q,k,v in one dispatch
  gemm_qkv<<<dim3(12, 8, B_), 256, 0, stream>>>(WQKV, HN, qbias, kbias, vbias,
                                                Q2, K2, V2, scale);
  // fused QK^T + softmax + PV + proj + residual -> out (fp32)
  attn_fused_k<<<256, 512, 0, stream>>>(Q2, K2, V2, Wpf, pbias, x, out);
}